// Round 7
// baseline (669.261 us; speedup 1.0000x reference)
//
#include <hip/hip_runtime.h>

typedef __bf16 bf16_t;
typedef __bf16 bf16x8 __attribute__((ext_vector_type(8)));
typedef float floatx4 __attribute__((ext_vector_type(4)));

constexpr int N = 100000;   // nodes
constexpr int E = 1600000;  // edges
constexpr int H = 128;      // feature dim
constexpr int G = 64;       // graphs
constexpr int C = 10;       // classes
constexpr int NBLK = (N + 255) / 256;  // 391

// Radix-bucketed CSR build: 8 dst-range buckets (one XCD L2 footprint each).
constexpr int NPART = 8;
constexpr int PART_SZ = (N + NPART - 1) / NPART;  // 12500
constexpr int BCAP = 262144;                      // slots per bucket (2^18)
constexpr int NCHUNK = 256;
constexpr int CHUNK_E = E / NCHUNK;  // 6250

__device__ inline float bflo(unsigned u) {
  return __builtin_bit_cast(float, u << 16);
}
__device__ inline float bfhi(unsigned u) {
  return __builtin_bit_cast(float, u & 0xffff0000u);
}
__device__ inline unsigned short f2b(float f) {
  return __builtin_bit_cast(unsigned short, (bf16_t)f);
}
__device__ inline unsigned pack2(float a, float b) {
  return (unsigned)f2b(a) | ((unsigned)f2b(b) << 16);
}

// ---------------------------------------------------------------------------
// fp32 -> bf16 convert (x once per call).
// ---------------------------------------------------------------------------
__global__ __launch_bounds__(256) void tobf_kernel(const float* __restrict__ x,
                                                   uint4* __restrict__ xb) {
  const int g = blockIdx.x * 256 + threadIdx.x;
  const float4 a = *(const float4*)(x + (size_t)g * 8);
  const float4 b = *(const float4*)(x + (size_t)g * 8 + 4);
  uint4 o;
  o.x = pack2(a.x, a.y);
  o.y = pack2(a.z, a.w);
  o.z = pack2(b.x, b.y);
  o.w = pack2(b.z, b.w);
  xb[g] = o;
}

// ---------------------------------------------------------------------------
// Pass A: bin edges into 8 dst-range buckets as (src,dst) pairs.
// ---------------------------------------------------------------------------
__global__ __launch_bounds__(256) void bin_kernel(const int* __restrict__ src,
                                                  const int* __restrict__ dst,
                                                  int* __restrict__ bcur,
                                                  uint2* __restrict__ pairs) {
  __shared__ int cnt8[NPART];
  __shared__ int base8[NPART];
  __shared__ int off8[NPART];
  const int tid = threadIdx.x;
  if (tid < NPART) {
    cnt8[tid] = 0;
    off8[tid] = 0;
  }
  __syncthreads();
  const int c0 = blockIdx.x * CHUNK_E;
  for (int e = c0 + tid; e < c0 + CHUNK_E; e += 256) {
    atomicAdd(&cnt8[dst[e] / PART_SZ], 1);
  }
  __syncthreads();
  if (tid < NPART) base8[tid] = atomicAdd(&bcur[tid], cnt8[tid]);
  __syncthreads();
  for (int e = c0 + tid; e < c0 + CHUNK_E; e += 256) {
    const int d = dst[e];
    const int s = src[e];
    const int p = d / PART_SZ;
    const int slot = base8[p] + atomicAdd(&off8[p], 1);
    pairs[((size_t)p << 18) + slot] = make_uint2((unsigned)s, (unsigned)d);
  }
}

// ---------------------------------------------------------------------------
// Bucketed histogram: blockIdx%8 = bucket -> deg slice (50 KB) is XCD-local.
// ---------------------------------------------------------------------------
__global__ __launch_bounds__(256) void histb_kernel(
    const uint2* __restrict__ pairs, const int* __restrict__ bcur,
    int* __restrict__ deg) {
  const int b = blockIdx.x & (NPART - 1);
  const int chunk = blockIdx.x >> 3;
  const int cb = bcur[b];
  const int e0 = (int)((long long)cb * chunk / 32);
  const int e1 = (int)((long long)cb * (chunk + 1) / 32);
  const uint2* pp = pairs + ((size_t)b << 18);
  for (int i = e0 + threadIdx.x; i < e1; i += 256)
    atomicAdd(&deg[pp[i].y], 1);
}

__global__ __launch_bounds__(256) void partial_kernel(
    const int* __restrict__ deg, int* __restrict__ partials) {
  __shared__ int sm[256];
  const int tid = threadIdx.x;
  const int i = blockIdx.x * 256 + tid;
  sm[tid] = (i < N) ? deg[i] : 0;
  __syncthreads();
  for (int off = 128; off > 0; off >>= 1) {
    if (tid < off) sm[tid] += sm[tid + off];
    __syncthreads();
  }
  if (tid == 0) partials[blockIdx.x] = sm[0];
}

__global__ __launch_bounds__(512) void scanp_kernel(
    const int* __restrict__ partials, int* __restrict__ blockbase) {
  __shared__ int p[512];
  const int t = threadIdx.x;
  p[t] = (t < NBLK) ? partials[t] : 0;
  __syncthreads();
  for (int off = 1; off < 512; off <<= 1) {
    int v = 0;
    if (t >= off) v = p[t - off];
    __syncthreads();
    p[t] += v;
    __syncthreads();
  }
  if (t < NBLK) blockbase[t] = (t == 0) ? 0 : p[t - 1];
}

__global__ __launch_bounds__(256) void expand_kernel(
    const int* __restrict__ deg, const int* __restrict__ blockbase,
    int* __restrict__ rowptr, int* __restrict__ cursor) {
  __shared__ int sm[256];
  const int tid = threadIdx.x;
  const int i = blockIdx.x * 256 + tid;
  const int d = (i < N) ? deg[i] : 0;
  sm[tid] = d;
  __syncthreads();
  for (int off = 1; off < 256; off <<= 1) {
    int v = 0;
    if (tid >= off) v = sm[tid - off];
    __syncthreads();
    sm[tid] += v;
    __syncthreads();
  }
  const int excl = sm[tid] - d + blockbase[blockIdx.x];
  if (i < N) {
    rowptr[i] = excl;
    cursor[i] = excl;
  }
  if (i == N - 1) rowptr[N] = excl + d;
}

// ---------------------------------------------------------------------------
// Bucketed fill: per bucket, cursor+csr region (~850 KB) is XCD-local.
// ---------------------------------------------------------------------------
__global__ __launch_bounds__(256) void fillb_kernel(
    const uint2* __restrict__ pairs, const int* __restrict__ bcur,
    int* __restrict__ cursor, int* __restrict__ csr_src) {
  const int b = blockIdx.x & (NPART - 1);
  const int chunk = blockIdx.x >> 3;
  const int cb = bcur[b];
  const int e0 = (int)((long long)cb * chunk / 32);
  const int e1 = (int)((long long)cb * (chunk + 1) / 32);
  const uint2* pp = pairs + ((size_t)b << 18);
  for (int i = e0 + threadIdx.x; i < e1; i += 256) {
    const uint2 e = pp[i];
    const int slot = atomicAdd(&cursor[e.y], 1);
    csr_src[slot] = (int)e.x;
  }
}

// ---------------------------------------------------------------------------
// Fused GIN layer: gather (pre = h + sum nbrs) -> MFMA MLP -> epilogue.
// IMPORTANT: hv (input) and h_out (output) must NOT alias — gather reads
// arbitrary rows of hv while other blocks write h_out (ping-pong buffers).
// MODE 0: h_out = bf16(LN(relu(o))); MODE 1: emb = o (fp32), h_out = relu(o).
// ---------------------------------------------------------------------------
template <int MODE>
__global__ __launch_bounds__(256, 4) void gnn_kernel(
    const uint4* __restrict__ hv,              // input h, bf16 rows as uint4
    const int* __restrict__ rowptr, const int* __restrict__ csr_src,
    const float* __restrict__ w1, const float* __restrict__ b1,
    const float* __restrict__ w2, const float* __restrict__ b2,
    const float* __restrict__ lng, const float* __restrict__ lnb,
    unsigned short* __restrict__ h_out,        // bf16 N x 128
    float* __restrict__ emb) {
  __shared__ unsigned short preS[32 * 136];
  __shared__ unsigned short hidS[32 * 136];
  __shared__ float outS[32 * 128];
  __shared__ int rowS[33];
  __shared__ float muS[32];
  __shared__ float rsS[32];

  const int tid = threadIdx.x;
  const int wave = tid >> 6;
  const int lane = tid & 63;
  const int quad = lane >> 4;
  const int l16 = lane & 15;

  union F8 { bf16x8 v; bf16_t e[8]; };

  bf16x8 w1f[4][2], w2f[4][2];
#pragma unroll
  for (int nn = 0; nn < 2; ++nn) {
    const int col = wave * 32 + nn * 16 + l16;
#pragma unroll
    for (int kt = 0; kt < 4; ++kt) {
      F8 t1, t2;
#pragma unroll
      for (int j = 0; j < 8; ++j) {
        const int k = kt * 32 + quad * 8 + j;
        t1.e[j] = (bf16_t)w1[k * H + col];
        t2.e[j] = (bf16_t)w2[k * H + col];
      }
      w1f[kt][nn] = t1.v;
      w2f[kt][nn] = t2.v;
    }
  }
  const float b1v[2] = {b1[wave * 32 + l16], b1[wave * 32 + 16 + l16]};
  const float b2v[2] = {b2[wave * 32 + l16], b2[wave * 32 + 16 + l16]};
  float lng0 = 0.f, lng1 = 0.f, lnb0 = 0.f, lnb1 = 0.f;
  const int c2 = (tid * 2) & 127;
  if (MODE == 0) {
    lng0 = lng[c2]; lng1 = lng[c2 + 1];
    lnb0 = lnb[c2]; lnb1 = lnb[c2 + 1];
  }

  const int grp = tid >> 4;  // 0..15
  const int l = tid & 15;

  for (int tile = blockIdx.x; tile < N / 32; tile += gridDim.x) {
    const int t0 = tile * 32;
    const size_t base = (size_t)t0 * H;

    if (tid < 33) rowS[tid] = rowptr[t0 + tid];
    __syncthreads();

    // ---- gather phase: preS[n] = h[n] + sum_{nbr} h[nbr] ----
#pragma unroll
    for (int rep = 0; rep < 2; ++rep) {
      const int n = grp + rep * 16;
      const int gn = t0 + n;
      const int r0 = rowS[n];
      const int r1 = rowS[n + 1];
      const uint4 v = hv[(size_t)gn * 16 + l];
      float a0 = bflo(v.x), a1 = bfhi(v.x), a2 = bflo(v.y), a3 = bfhi(v.y);
      float a4 = bflo(v.z), a5 = bfhi(v.z), a6 = bflo(v.w), a7 = bfhi(v.w);
      int s = r0;
      for (; s + 1 < r1; s += 2) {
        const uint4 u = hv[(size_t)csr_src[s] * 16 + l];
        const uint4 w = hv[(size_t)csr_src[s + 1] * 16 + l];
        a0 += bflo(u.x); a1 += bfhi(u.x); a2 += bflo(u.y); a3 += bfhi(u.y);
        a4 += bflo(u.z); a5 += bfhi(u.z); a6 += bflo(u.w); a7 += bfhi(u.w);
        a0 += bflo(w.x); a1 += bfhi(w.x); a2 += bflo(w.y); a3 += bfhi(w.y);
        a4 += bflo(w.z); a5 += bfhi(w.z); a6 += bflo(w.w); a7 += bfhi(w.w);
      }
      if (s < r1) {
        const uint4 u = hv[(size_t)csr_src[s] * 16 + l];
        a0 += bflo(u.x); a1 += bfhi(u.x); a2 += bflo(u.y); a3 += bfhi(u.y);
        a4 += bflo(u.z); a5 += bfhi(u.z); a6 += bflo(u.w); a7 += bfhi(u.w);
      }
      uint4 o;
      o.x = pack2(a0, a1);
      o.y = pack2(a2, a3);
      o.z = pack2(a4, a5);
      o.w = pack2(a6, a7);
      *(uint4*)&preS[n * 136 + l * 8] = o;
    }
    __syncthreads();

    // ---- GEMM1: hid = relu(pre @ W1 + b1) ----
    {
      floatx4 acc[2][2];
#pragma unroll
      for (int i = 0; i < 2; ++i)
#pragma unroll
        for (int j = 0; j < 2; ++j) acc[i][j] = {0.f, 0.f, 0.f, 0.f};
#pragma unroll
      for (int kt = 0; kt < 4; ++kt) {
        const int kc = kt * 32 + quad * 8;
        const bf16x8 a0 =
            __builtin_bit_cast(bf16x8, *(const uint4*)&preS[l16 * 136 + kc]);
        const bf16x8 a1 = __builtin_bit_cast(
            bf16x8, *(const uint4*)&preS[(16 + l16) * 136 + kc]);
        acc[0][0] = __builtin_amdgcn_mfma_f32_16x16x32_bf16(a0, w1f[kt][0],
                                                            acc[0][0], 0, 0, 0);
        acc[0][1] = __builtin_amdgcn_mfma_f32_16x16x32_bf16(a0, w1f[kt][1],
                                                            acc[0][1], 0, 0, 0);
        acc[1][0] = __builtin_amdgcn_mfma_f32_16x16x32_bf16(a1, w1f[kt][0],
                                                            acc[1][0], 0, 0, 0);
        acc[1][1] = __builtin_amdgcn_mfma_f32_16x16x32_bf16(a1, w1f[kt][1],
                                                            acc[1][1], 0, 0, 0);
      }
#pragma unroll
      for (int mt = 0; mt < 2; ++mt)
#pragma unroll
        for (int nn = 0; nn < 2; ++nn) {
          const int col = wave * 32 + nn * 16 + l16;
#pragma unroll
          for (int r = 0; r < 4; ++r) {
            const int row = mt * 16 + quad * 4 + r;
            const float v = fmaxf(acc[mt][nn][r] + b1v[nn], 0.f);
            hidS[row * 136 + col] = f2b(v);
          }
        }
    }
    __syncthreads();

    // ---- GEMM2: o = hid @ W2 + b2 ----
    {
      floatx4 acc[2][2];
#pragma unroll
      for (int i = 0; i < 2; ++i)
#pragma unroll
        for (int j = 0; j < 2; ++j) acc[i][j] = {0.f, 0.f, 0.f, 0.f};
#pragma unroll
      for (int kt = 0; kt < 4; ++kt) {
        const int kc = kt * 32 + quad * 8;
        const bf16x8 a0 =
            __builtin_bit_cast(bf16x8, *(const uint4*)&hidS[l16 * 136 + kc]);
        const bf16x8 a1 = __builtin_bit_cast(
            bf16x8, *(const uint4*)&hidS[(16 + l16) * 136 + kc]);
        acc[0][0] = __builtin_amdgcn_mfma_f32_16x16x32_bf16(a0, w2f[kt][0],
                                                            acc[0][0], 0, 0, 0);
        acc[0][1] = __builtin_amdgcn_mfma_f32_16x16x32_bf16(a0, w2f[kt][1],
                                                            acc[0][1], 0, 0, 0);
        acc[1][0] = __builtin_amdgcn_mfma_f32_16x16x32_bf16(a1, w2f[kt][0],
                                                            acc[1][0], 0, 0, 0);
        acc[1][1] = __builtin_amdgcn_mfma_f32_16x16x32_bf16(a1, w2f[kt][1],
                                                            acc[1][1], 0, 0, 0);
      }
#pragma unroll
      for (int mt = 0; mt < 2; ++mt)
#pragma unroll
        for (int nn = 0; nn < 2; ++nn) {
          const int col = wave * 32 + nn * 16 + l16;
#pragma unroll
          for (int r = 0; r < 4; ++r) {
            const int row = mt * 16 + quad * 4 + r;
            float v = acc[mt][nn][r] + b2v[nn];
            if (MODE == 0) v = fmaxf(v, 0.f);
            outS[row * 128 + col] = v;
          }
        }
    }
    __syncthreads();

    if (MODE == 0) {
      const int n = tid >> 3;
      const int j = tid & 7;
      float s = 0.f, sq = 0.f;
#pragma unroll
      for (int t = 0; t < 16; ++t) {
        const float v = outS[n * 128 + j + 8 * t];
        s += v;
        sq += v * v;
      }
      s += __shfl_xor(s, 1); sq += __shfl_xor(sq, 1);
      s += __shfl_xor(s, 2); sq += __shfl_xor(sq, 2);
      s += __shfl_xor(s, 4); sq += __shfl_xor(sq, 4);
      if (j == 0) {
        const float mu = s * (1.f / H);
        const float var = sq * (1.f / H) - mu * mu;
        muS[n] = mu;
        rsS[n] = rsqrtf(var + 1e-5f);
      }
      __syncthreads();
      unsigned* ho = (unsigned*)(h_out + base);
#pragma unroll
      for (int it = 0; it < 8; ++it) {
        const int idx = it * 512 + tid * 2;
        const int row = idx >> 7;
        const float mu = muS[row], rs = rsS[row];
        const float v0 = (outS[idx] - mu) * rs * lng0 + lnb0;
        const float v1 = (outS[idx + 1] - mu) * rs * lng1 + lnb1;
        ho[idx >> 1] = pack2(v0, v1);
      }
    } else {
      unsigned* ho = (unsigned*)(h_out + base);
#pragma unroll
      for (int it = 0; it < 8; ++it) {
        const int idx = it * 512 + tid * 2;
        const float v0 = outS[idx];
        const float v1 = outS[idx + 1];
        *(float2*)&emb[base + idx] = make_float2(v0, v1);
        ho[idx >> 1] = pack2(fmaxf(v0, 0.f), fmaxf(v1, 0.f));
      }
    }
    __syncthreads();  // protect preS/hidS/outS before next tile
  }
}

// ---------------------------------------------------------------------------
// Mean pool: cooperative segmented reduction over sorted `batch`.
// ---------------------------------------------------------------------------
__global__ __launch_bounds__(256) void pool_kernel(
    const uint4* __restrict__ hv, const int* __restrict__ batch,
    float* __restrict__ pooled, float* __restrict__ cnt) {
  __shared__ int bs[256];
  __shared__ float smr[512];
  __shared__ int endS;
  const int tid = threadIdx.x;
  const int c0 = blockIdx.x * 256;
  const int len = min(256, N - c0);
  if (tid < len) bs[tid] = batch[c0 + tid];
  __syncthreads();

  const int nl = tid >> 4;
  const int fg = tid & 15;
  const int wave = tid >> 6;
  const int lane = tid & 63;

  int start = 0;
  while (start < len) {
    const int g = bs[start];
    if (tid == 0) endS = len;
    __syncthreads();
    for (int i = start + tid; i < len; i += 256)
      if (bs[i] != g) atomicMin(&endS, i);
    __syncthreads();
    const int end = endS;

    float a0 = 0.f, a1 = 0.f, a2 = 0.f, a3 = 0.f;
    float a4 = 0.f, a5 = 0.f, a6 = 0.f, a7 = 0.f;
    for (int i = start + nl; i < end; i += 16) {
      const uint4 u = hv[(size_t)(c0 + i) * 16 + fg];
      a0 += bflo(u.x); a1 += bfhi(u.x); a2 += bflo(u.y); a3 += bfhi(u.y);
      a4 += bflo(u.z); a5 += bfhi(u.z); a6 += bflo(u.w); a7 += bfhi(u.w);
    }
    a0 += __shfl_xor(a0, 16); a1 += __shfl_xor(a1, 16);
    a2 += __shfl_xor(a2, 16); a3 += __shfl_xor(a3, 16);
    a4 += __shfl_xor(a4, 16); a5 += __shfl_xor(a5, 16);
    a6 += __shfl_xor(a6, 16); a7 += __shfl_xor(a7, 16);
    a0 += __shfl_xor(a0, 32); a1 += __shfl_xor(a1, 32);
    a2 += __shfl_xor(a2, 32); a3 += __shfl_xor(a3, 32);
    a4 += __shfl_xor(a4, 32); a5 += __shfl_xor(a5, 32);
    a6 += __shfl_xor(a6, 32); a7 += __shfl_xor(a7, 32);
    if (lane < 16) {
      float* d = &smr[wave * 128 + lane * 8];
      d[0] = a0; d[1] = a1; d[2] = a2; d[3] = a3;
      d[4] = a4; d[5] = a5; d[6] = a6; d[7] = a7;
    }
    __syncthreads();
    if (tid < 128) {
      const float s =
          smr[tid] + smr[128 + tid] + smr[256 + tid] + smr[384 + tid];
      atomicAdd(&pooled[g * H + tid], s);
    }
    if (tid == 0) atomicAdd(&cnt[g], (float)(end - start));
    __syncthreads();
    start = end;
  }
}

// ---------------------------------------------------------------------------
// Head: pooled/cnt -> z = pooled@pw1+pb1 -> logits -> log_softmax
// ---------------------------------------------------------------------------
__global__ __launch_bounds__(128) void head_kernel(
    const float* __restrict__ pooled, const float* __restrict__ cnt,
    const float* __restrict__ pw1, const float* __restrict__ pb1,
    const float* __restrict__ pw2, const float* __restrict__ pb2,
    float* __restrict__ out_logp) {
  __shared__ float p[H];
  __shared__ float z[H];
  __shared__ float l[C];
  const int g = blockIdx.x;
  const int f = threadIdx.x;
  const float c = fmaxf(cnt[g], 1.f);
  p[f] = pooled[g * H + f] / c;
  __syncthreads();
  float a = pb1[f];
  for (int k = 0; k < H; ++k) a += p[k] * pw1[k * H + f];
  z[f] = a;
  __syncthreads();
  if (f < C) {
    float a2 = pb2[f];
    for (int k = 0; k < H; ++k) a2 += z[k] * pw2[k * C + f];
    l[f] = a2;
  }
  __syncthreads();
  if (f == 0) {
    float m = l[0];
    for (int i = 1; i < C; ++i) m = fmaxf(m, l[i]);
    float s = 0.f;
    for (int i = 0; i < C; ++i) s += expf(l[i] - m);
    const float lse = m + logf(s);
    for (int i = 0; i < C; ++i) out_logp[g * C + i] = l[i] - lse;
  }
}

extern "C" void kernel_launch(void* const* d_in, const int* in_sizes, int n_in,
                              void* d_out, int out_size, void* d_ws,
                              size_t ws_size, hipStream_t stream) {
  const float* x = (const float*)d_in[0];
  const int* ei = (const int*)d_in[1];
  const int* src = ei;
  const int* dst = ei + E;
  const int* batch = (const int*)d_in[2];
  const float* w1_0 = (const float*)d_in[3];
  const float* b1_0 = (const float*)d_in[4];
  const float* w2_0 = (const float*)d_in[5];
  const float* b2_0 = (const float*)d_in[6];
  const float* w1_1 = (const float*)d_in[7];
  const float* b1_1 = (const float*)d_in[8];
  const float* w2_1 = (const float*)d_in[9];
  const float* b2_1 = (const float*)d_in[10];
  const float* w1_2 = (const float*)d_in[11];
  const float* b1_2 = (const float*)d_in[12];
  const float* w2_2 = (const float*)d_in[13];
  const float* b2_2 = (const float*)d_in[14];
  const float* ln_g0 = (const float*)d_in[15];
  const float* ln_b0 = (const float*)d_in[16];
  const float* ln_g1 = (const float*)d_in[17];
  const float* ln_b1 = (const float*)d_in[18];
  const float* pw1 = (const float*)d_in[19];
  const float* pb1 = (const float*)d_in[20];
  const float* pw2 = (const float*)d_in[21];
  const float* pb2 = (const float*)d_in[22];

  // ws layout: ping-pong feature buffers (xb, h1, h2) — gnn_kernel input and
  // output must never alias.
  unsigned short* xb = (unsigned short*)d_ws;          // N*H bf16
  unsigned short* h1 = xb + (size_t)N * H;             // N*H bf16
  unsigned short* h2 = h1 + (size_t)N * H;             // N*H bf16
  uint2* pairs = (uint2*)(h2 + (size_t)N * H);         // 8*BCAP uint2
  int* deg = (int*)(pairs + (size_t)NPART * BCAP);     // N
  int* bcur = deg + N;                                 // 8
  int* rowptr = bcur + NPART;                          // N+1
  int* cursor = rowptr + N + 1;                        // N
  int* csr_src = cursor + N;                           // E
  int* partials = csr_src + E;                         // NBLK
  int* blockbase = partials + NBLK;                    // NBLK
  float* pooled = (float*)(blockbase + NBLK);          // G*H
  float* cnt = pooled + (size_t)G * H;                 // G
  float* emb = (float*)d_out;                          // N*H fp32
  float* logp = emb + (size_t)N * H;                   // G*C

  // ---- x -> bf16 ----
  tobf_kernel<<<N * H / (256 * 8), 256, 0, stream>>>(x, (uint4*)xb);

  // ---- CSR build: bin -> bucketed hist -> scan -> bucketed fill ----
  hipMemsetAsync(deg, 0, (size_t)(N + NPART) * sizeof(int), stream);  // +bcur
  bin_kernel<<<NCHUNK, 256, 0, stream>>>(src, dst, bcur, pairs);
  histb_kernel<<<NPART * 32, 256, 0, stream>>>(pairs, bcur, deg);
  partial_kernel<<<NBLK, 256, 0, stream>>>(deg, partials);
  scanp_kernel<<<1, 512, 0, stream>>>(partials, blockbase);
  expand_kernel<<<NBLK, 256, 0, stream>>>(deg, blockbase, rowptr, cursor);
  fillb_kernel<<<NPART * 32, 256, 0, stream>>>(pairs, bcur, cursor, csr_src);

  // ---- fused GIN layers (ping-pong: xb -> h1 -> h2 -> h1) ----
  gnn_kernel<0><<<1024, 256, 0, stream>>>((const uint4*)xb, rowptr, csr_src,
                                          w1_0, b1_0, w2_0, b2_0, ln_g0, ln_b0,
                                          h1, nullptr);
  gnn_kernel<0><<<1024, 256, 0, stream>>>((const uint4*)h1, rowptr, csr_src,
                                          w1_1, b1_1, w2_1, b2_1, ln_g1, ln_b1,
                                          h2, nullptr);
  gnn_kernel<1><<<1024, 256, 0, stream>>>((const uint4*)h2, rowptr, csr_src,
                                          w1_2, b1_2, w2_2, b2_2, nullptr,
                                          nullptr, h1, emb);

  // ---- pool + head ----
  hipMemsetAsync(pooled, 0, (size_t)(G * H + G) * sizeof(float), stream);
  pool_kernel<<<NBLK, 256, 0, stream>>>((const uint4*)h1, batch, pooled, cnt);
  head_kernel<<<G, 128, 0, stream>>>(pooled, cnt, pw1, pb1, pw2, pb2, logp);
}

// Round 8
// 610.678 us; speedup vs baseline: 1.0959x; 1.0959x over previous
//
#include <hip/hip_runtime.h>

typedef __bf16 bf16_t;
typedef __bf16 bf16x8 __attribute__((ext_vector_type(8)));
typedef float floatx4 __attribute__((ext_vector_type(4)));

constexpr int N = 100000;   // nodes
constexpr int E = 1600000;  // edges
constexpr int H = 128;      // feature dim
constexpr int G = 64;       // graphs
constexpr int C = 10;       // classes
constexpr int NBLK = (N + 255) / 256;  // 391

// hist: 16 partitions, LDS-privatized histograms, partition -> XCD pinned.
constexpr int HPART = 16;
constexpr int HPART_SZ = N / HPART;      // 6250
constexpr int HCHUNK = 32;
constexpr int HCHUNK_E = E / HCHUNK;     // 50000
// fill: 8 partitions (cursor+csr slice L2-resident), 256 edge chunks.
constexpr int FPART = 8;
constexpr int FPART_SZ = (N + FPART - 1) / FPART;  // 12500
constexpr int FCHUNK = 256;
constexpr int FCHUNK_E = E / FCHUNK;     // 6250

__device__ inline float bflo(unsigned u) {
  return __builtin_bit_cast(float, u << 16);
}
__device__ inline float bfhi(unsigned u) {
  return __builtin_bit_cast(float, u & 0xffff0000u);
}
__device__ inline unsigned short f2b(float f) {
  return __builtin_bit_cast(unsigned short, (bf16_t)f);
}
__device__ inline unsigned pack2(float a, float b) {
  return (unsigned)f2b(a) | ((unsigned)f2b(b) << 16);
}

// ---------------------------------------------------------------------------
// fp32 -> bf16 convert (x once per call).
// ---------------------------------------------------------------------------
__global__ __launch_bounds__(256) void tobf_kernel(const float* __restrict__ x,
                                                   uint4* __restrict__ xb) {
  const int g = blockIdx.x * 256 + threadIdx.x;
  const float4 a = *(const float4*)(x + (size_t)g * 8);
  const float4 b = *(const float4*)(x + (size_t)g * 8 + 4);
  uint4 o;
  o.x = pack2(a.x, a.y);
  o.y = pack2(a.z, a.w);
  o.z = pack2(b.x, b.y);
  o.w = pack2(b.z, b.w);
  xb[g] = o;
}

// ---------------------------------------------------------------------------
// Histogram with LDS privatization: partition = blockIdx&15 (XCD-pinned),
// 25 KB LDS hist per block; merge is coalesced global atomics on the slice.
// Streaming dst reads are nontemporal (don't pollute L2).
// ---------------------------------------------------------------------------
__global__ __launch_bounds__(256) void hist_kernel(const int* __restrict__ dst,
                                                   int* __restrict__ deg) {
  __shared__ int hloc[HPART_SZ];
  const int part = blockIdx.x & (HPART - 1);
  const int chunk = blockIdx.x >> 4;
  const int lo = part * HPART_SZ;
  const int tid = threadIdx.x;
  for (int i = tid; i < HPART_SZ; i += 256) hloc[i] = 0;
  __syncthreads();
  const int c0 = chunk * HCHUNK_E;
  for (int e = c0 + tid; e < c0 + HCHUNK_E; e += 256) {
    const int d = __builtin_nontemporal_load(dst + e);
    const int r = d - lo;
    if ((unsigned)r < (unsigned)HPART_SZ) atomicAdd(&hloc[r], 1);
  }
  __syncthreads();
  for (int i = tid; i < HPART_SZ; i += 256) {
    const int v = hloc[i];
    if (v) atomicAdd(&deg[lo + i], v);
  }
}

__global__ __launch_bounds__(256) void partial_kernel(
    const int* __restrict__ deg, int* __restrict__ partials) {
  __shared__ int sm[256];
  const int tid = threadIdx.x;
  const int i = blockIdx.x * 256 + tid;
  sm[tid] = (i < N) ? deg[i] : 0;
  __syncthreads();
  for (int off = 128; off > 0; off >>= 1) {
    if (tid < off) sm[tid] += sm[tid + off];
    __syncthreads();
  }
  if (tid == 0) partials[blockIdx.x] = sm[0];
}

__global__ __launch_bounds__(512) void scanp_kernel(
    const int* __restrict__ partials, int* __restrict__ blockbase) {
  __shared__ int p[512];
  const int t = threadIdx.x;
  p[t] = (t < NBLK) ? partials[t] : 0;
  __syncthreads();
  for (int off = 1; off < 512; off <<= 1) {
    int v = 0;
    if (t >= off) v = p[t - off];
    __syncthreads();
    p[t] += v;
    __syncthreads();
  }
  if (t < NBLK) blockbase[t] = (t == 0) ? 0 : p[t - 1];
}

__global__ __launch_bounds__(256) void expand_kernel(
    const int* __restrict__ deg, const int* __restrict__ blockbase,
    int* __restrict__ rowptr, int* __restrict__ cursor) {
  __shared__ int sm[256];
  const int tid = threadIdx.x;
  const int i = blockIdx.x * 256 + tid;
  const int d = (i < N) ? deg[i] : 0;
  sm[tid] = d;
  __syncthreads();
  for (int off = 1; off < 256; off <<= 1) {
    int v = 0;
    if (tid >= off) v = sm[tid - off];
    __syncthreads();
    sm[tid] += v;
    __syncthreads();
  }
  const int excl = sm[tid] - d + blockbase[blockIdx.x];
  if (i < N) {
    rowptr[i] = excl;
    cursor[i] = excl;
  }
  if (i == N - 1) rowptr[N] = excl + d;
}

// ---------------------------------------------------------------------------
// Partitioned fill: blockIdx&7 = dst range (XCD-pinned cursor/csr slice);
// nontemporal src/dst reads so the stream doesn't evict dirty csr lines.
// ---------------------------------------------------------------------------
__global__ __launch_bounds__(256) void fill_kernel(const int* __restrict__ src,
                                                   const int* __restrict__ dst,
                                                   int* __restrict__ cursor,
                                                   int* __restrict__ csr_src) {
  const int part = blockIdx.x & (FPART - 1);
  const int chunk = blockIdx.x >> 3;
  const int lo = part * FPART_SZ;
  const int hi = lo + FPART_SZ;
  const int c0 = chunk * FCHUNK_E;
  for (int e = c0 + threadIdx.x; e < c0 + FCHUNK_E; e += 256) {
    const int d = __builtin_nontemporal_load(dst + e);
    if (d >= lo && d < hi) {
      const int s = __builtin_nontemporal_load(src + e);
      const int slot = atomicAdd(&cursor[d], 1);
      csr_src[slot] = s;
    }
  }
}

// ---------------------------------------------------------------------------
// Gather aggregation (bf16): pre[i] = h[i] + sum_{j in nbrs(i)} h[j]
// 16 lanes/node, uint4 (8 bf16)/lane, unroll 4 (4 row-loads in flight).
// ---------------------------------------------------------------------------
__global__ __launch_bounds__(256) void gather_kernel(
    const uint4* __restrict__ h, const int* __restrict__ rowptr,
    const int* __restrict__ csr_src, uint4* __restrict__ pre) {
  const int node = blockIdx.x * 16 + (threadIdx.x >> 4);
  const int l = threadIdx.x & 15;
  const int r0 = rowptr[node];
  const int r1 = rowptr[node + 1];
  const uint4 v = h[(size_t)node * 16 + l];
  float a0 = bflo(v.x), a1 = bfhi(v.x), a2 = bflo(v.y), a3 = bfhi(v.y);
  float a4 = bflo(v.z), a5 = bfhi(v.z), a6 = bflo(v.w), a7 = bfhi(v.w);
  int s = r0;
  for (; s + 3 < r1; s += 4) {
    const int i0 = csr_src[s], i1 = csr_src[s + 1];
    const int i2 = csr_src[s + 2], i3 = csr_src[s + 3];
    const uint4 u0 = h[(size_t)i0 * 16 + l];
    const uint4 u1 = h[(size_t)i1 * 16 + l];
    const uint4 u2 = h[(size_t)i2 * 16 + l];
    const uint4 u3 = h[(size_t)i3 * 16 + l];
    a0 += bflo(u0.x); a1 += bfhi(u0.x); a2 += bflo(u0.y); a3 += bfhi(u0.y);
    a4 += bflo(u0.z); a5 += bfhi(u0.z); a6 += bflo(u0.w); a7 += bfhi(u0.w);
    a0 += bflo(u1.x); a1 += bfhi(u1.x); a2 += bflo(u1.y); a3 += bfhi(u1.y);
    a4 += bflo(u1.z); a5 += bfhi(u1.z); a6 += bflo(u1.w); a7 += bfhi(u1.w);
    a0 += bflo(u2.x); a1 += bfhi(u2.x); a2 += bflo(u2.y); a3 += bfhi(u2.y);
    a4 += bflo(u2.z); a5 += bfhi(u2.z); a6 += bflo(u2.w); a7 += bfhi(u2.w);
    a0 += bflo(u3.x); a1 += bfhi(u3.x); a2 += bflo(u3.y); a3 += bfhi(u3.y);
    a4 += bflo(u3.z); a5 += bfhi(u3.z); a6 += bflo(u3.w); a7 += bfhi(u3.w);
  }
  for (; s < r1; ++s) {
    const uint4 u = h[(size_t)csr_src[s] * 16 + l];
    a0 += bflo(u.x); a1 += bfhi(u.x); a2 += bflo(u.y); a3 += bfhi(u.y);
    a4 += bflo(u.z); a5 += bfhi(u.z); a6 += bflo(u.w); a7 += bfhi(u.w);
  }
  uint4 o;
  o.x = pack2(a0, a1);
  o.y = pack2(a2, a3);
  o.z = pack2(a4, a5);
  o.w = pack2(a6, a7);
  pre[(size_t)node * 16 + l] = o;
}

// ---------------------------------------------------------------------------
// MFMA bf16 GIN MLP. 32-node tiles; W1/W2 register fragments; preS/hidS rows
// padded to 136 shorts; outS rows padded to 132 floats (bank shift 4 -> the
// quad-stores 2-way alias = free; 128 was 4-way conflicted).
// MODE 0: h_out = bf16(LN(relu(o))); MODE 1: emb = o (fp32), h_out = relu(o).
// ---------------------------------------------------------------------------
template <int MODE>
__global__ __launch_bounds__(256, 1) void mlp_kernel(
    const unsigned short* __restrict__ pre_g,  // bf16 N x 128
    const float* __restrict__ w1, const float* __restrict__ b1,
    const float* __restrict__ w2, const float* __restrict__ b2,
    const float* __restrict__ lng, const float* __restrict__ lnb,
    unsigned short* __restrict__ h_out,        // bf16 N x 128
    float* __restrict__ emb) {
  __shared__ unsigned short preS[32 * 136];
  __shared__ unsigned short hidS[32 * 136];
  __shared__ float outS[32 * 132];
  __shared__ float muS[32];
  __shared__ float rsS[32];

  const int tid = threadIdx.x;
  const int wave = tid >> 6;
  const int lane = tid & 63;
  const int quad = lane >> 4;
  const int l16 = lane & 15;

  union F8 { bf16x8 v; bf16_t e[8]; };

  bf16x8 w1f[4][2], w2f[4][2];
#pragma unroll
  for (int nn = 0; nn < 2; ++nn) {
    const int col = wave * 32 + nn * 16 + l16;
#pragma unroll
    for (int kt = 0; kt < 4; ++kt) {
      F8 t1, t2;
#pragma unroll
      for (int j = 0; j < 8; ++j) {
        const int k = kt * 32 + quad * 8 + j;
        t1.e[j] = (bf16_t)w1[k * H + col];
        t2.e[j] = (bf16_t)w2[k * H + col];
      }
      w1f[kt][nn] = t1.v;
      w2f[kt][nn] = t2.v;
    }
  }
  const float b1v[2] = {b1[wave * 32 + l16], b1[wave * 32 + 16 + l16]};
  const float b2v[2] = {b2[wave * 32 + l16], b2[wave * 32 + 16 + l16]};
  float lng0 = 0.f, lng1 = 0.f, lnb0 = 0.f, lnb1 = 0.f;
  const int c2 = (tid * 2) & 127;
  if (MODE == 0) {
    lng0 = lng[c2]; lng1 = lng[c2 + 1];
    lnb0 = lnb[c2]; lnb1 = lnb[c2 + 1];
  }

  for (int tile = blockIdx.x; tile < N / 32; tile += gridDim.x) {
    const size_t base = (size_t)tile * 32 * H;
    {
      const uint4* srcp = (const uint4*)(pre_g + base);
#pragma unroll
      for (int it = 0; it < 2; ++it) {
        const int chunk = it * 256 + tid;
        const int row = chunk >> 4;
        const int colc = (chunk & 15) * 8;
        *(uint4*)&preS[row * 136 + colc] = srcp[chunk];
      }
    }
    __syncthreads();

    // GEMM1: hid = relu(pre @ W1 + b1)
    {
      floatx4 acc[2][2];
#pragma unroll
      for (int i = 0; i < 2; ++i)
#pragma unroll
        for (int j = 0; j < 2; ++j) acc[i][j] = {0.f, 0.f, 0.f, 0.f};
#pragma unroll
      for (int kt = 0; kt < 4; ++kt) {
        const int kc = kt * 32 + quad * 8;
        const bf16x8 a0 =
            __builtin_bit_cast(bf16x8, *(const uint4*)&preS[l16 * 136 + kc]);
        const bf16x8 a1 = __builtin_bit_cast(
            bf16x8, *(const uint4*)&preS[(16 + l16) * 136 + kc]);
        acc[0][0] = __builtin_amdgcn_mfma_f32_16x16x32_bf16(a0, w1f[kt][0],
                                                            acc[0][0], 0, 0, 0);
        acc[0][1] = __builtin_amdgcn_mfma_f32_16x16x32_bf16(a0, w1f[kt][1],
                                                            acc[0][1], 0, 0, 0);
        acc[1][0] = __builtin_amdgcn_mfma_f32_16x16x32_bf16(a1, w1f[kt][0],
                                                            acc[1][0], 0, 0, 0);
        acc[1][1] = __builtin_amdgcn_mfma_f32_16x16x32_bf16(a1, w1f[kt][1],
                                                            acc[1][1], 0, 0, 0);
      }
#pragma unroll
      for (int mt = 0; mt < 2; ++mt)
#pragma unroll
        for (int nn = 0; nn < 2; ++nn) {
          const int col = wave * 32 + nn * 16 + l16;
#pragma unroll
          for (int r = 0; r < 4; ++r) {
            const int row = mt * 16 + quad * 4 + r;
            const float v = fmaxf(acc[mt][nn][r] + b1v[nn], 0.f);
            hidS[row * 136 + col] = f2b(v);
          }
        }
    }
    __syncthreads();

    // GEMM2: o = hid @ W2 + b2
    {
      floatx4 acc[2][2];
#pragma unroll
      for (int i = 0; i < 2; ++i)
#pragma unroll
        for (int j = 0; j < 2; ++j) acc[i][j] = {0.f, 0.f, 0.f, 0.f};
#pragma unroll
      for (int kt = 0; kt < 4; ++kt) {
        const int kc = kt * 32 + quad * 8;
        const bf16x8 a0 =
            __builtin_bit_cast(bf16x8, *(const uint4*)&hidS[l16 * 136 + kc]);
        const bf16x8 a1 = __builtin_bit_cast(
            bf16x8, *(const uint4*)&hidS[(16 + l16) * 136 + kc]);
        acc[0][0] = __builtin_amdgcn_mfma_f32_16x16x32_bf16(a0, w2f[kt][0],
                                                            acc[0][0], 0, 0, 0);
        acc[0][1] = __builtin_amdgcn_mfma_f32_16x16x32_bf16(a0, w2f[kt][1],
                                                            acc[0][1], 0, 0, 0);
        acc[1][0] = __builtin_amdgcn_mfma_f32_16x16x32_bf16(a1, w2f[kt][0],
                                                            acc[1][0], 0, 0, 0);
        acc[1][1] = __builtin_amdgcn_mfma_f32_16x16x32_bf16(a1, w2f[kt][1],
                                                            acc[1][1], 0, 0, 0);
      }
#pragma unroll
      for (int mt = 0; mt < 2; ++mt)
#pragma unroll
        for (int nn = 0; nn < 2; ++nn) {
          const int col = wave * 32 + nn * 16 + l16;
#pragma unroll
          for (int r = 0; r < 4; ++r) {
            const int row = mt * 16 + quad * 4 + r;
            float v = acc[mt][nn][r] + b2v[nn];
            if (MODE == 0) v = fmaxf(v, 0.f);
            outS[row * 132 + col] = v;
          }
        }
    }
    __syncthreads();

    if (MODE == 0) {
      const int n = tid >> 3;
      const int j = tid & 7;
      float s = 0.f, sq = 0.f;
#pragma unroll
      for (int t = 0; t < 16; ++t) {
        const float v = outS[n * 132 + j + 8 * t];
        s += v;
        sq += v * v;
      }
      s += __shfl_xor(s, 1); sq += __shfl_xor(sq, 1);
      s += __shfl_xor(s, 2); sq += __shfl_xor(sq, 2);
      s += __shfl_xor(s, 4); sq += __shfl_xor(sq, 4);
      if (j == 0) {
        const float mu = s * (1.f / H);
        const float var = sq * (1.f / H) - mu * mu;
        muS[n] = mu;
        rsS[n] = rsqrtf(var + 1e-5f);
      }
      __syncthreads();
      unsigned* ho = (unsigned*)(h_out + base);
#pragma unroll
      for (int it = 0; it < 8; ++it) {
        const int idx = it * 512 + tid * 2;
        const int row = idx >> 7;
        const int k = idx & 127;
        const float mu = muS[row], rs = rsS[row];
        const float v0 = (outS[row * 132 + k] - mu) * rs * lng0 + lnb0;
        const float v1 = (outS[row * 132 + k + 1] - mu) * rs * lng1 + lnb1;
        ho[idx >> 1] = pack2(v0, v1);
      }
    } else {
      unsigned* ho = (unsigned*)(h_out + base);
#pragma unroll
      for (int it = 0; it < 8; ++it) {
        const int idx = it * 512 + tid * 2;
        const int row = idx >> 7;
        const int k = idx & 127;
        const float v0 = outS[row * 132 + k];
        const float v1 = outS[row * 132 + k + 1];
        *(float2*)&emb[base + idx] = make_float2(v0, v1);
        ho[idx >> 1] = pack2(fmaxf(v0, 0.f), fmaxf(v1, 0.f));
      }
    }
    __syncthreads();
  }
}

// ---------------------------------------------------------------------------
// Mean pool: cooperative segmented reduction over sorted `batch`.
// ---------------------------------------------------------------------------
__global__ __launch_bounds__(256) void pool_kernel(
    const uint4* __restrict__ hv, const int* __restrict__ batch,
    float* __restrict__ pooled, float* __restrict__ cnt) {
  __shared__ int bs[256];
  __shared__ float smr[512];
  __shared__ int endS;
  const int tid = threadIdx.x;
  const int c0 = blockIdx.x * 256;
  const int len = min(256, N - c0);
  if (tid < len) bs[tid] = batch[c0 + tid];
  __syncthreads();

  const int nl = tid >> 4;
  const int fg = tid & 15;
  const int wave = tid >> 6;
  const int lane = tid & 63;

  int start = 0;
  while (start < len) {
    const int g = bs[start];
    if (tid == 0) endS = len;
    __syncthreads();
    for (int i = start + tid; i < len; i += 256)
      if (bs[i] != g) atomicMin(&endS, i);
    __syncthreads();
    const int end = endS;

    float a0 = 0.f, a1 = 0.f, a2 = 0.f, a3 = 0.f;
    float a4 = 0.f, a5 = 0.f, a6 = 0.f, a7 = 0.f;
    for (int i = start + nl; i < end; i += 16) {
      const uint4 u = hv[(size_t)(c0 + i) * 16 + fg];
      a0 += bflo(u.x); a1 += bfhi(u.x); a2 += bflo(u.y); a3 += bfhi(u.y);
      a4 += bflo(u.z); a5 += bfhi(u.z); a6 += bflo(u.w); a7 += bfhi(u.w);
    }
    a0 += __shfl_xor(a0, 16); a1 += __shfl_xor(a1, 16);
    a2 += __shfl_xor(a2, 16); a3 += __shfl_xor(a3, 16);
    a4 += __shfl_xor(a4, 16); a5 += __shfl_xor(a5, 16);
    a6 += __shfl_xor(a6, 16); a7 += __shfl_xor(a7, 16);
    a0 += __shfl_xor(a0, 32); a1 += __shfl_xor(a1, 32);
    a2 += __shfl_xor(a2, 32); a3 += __shfl_xor(a3, 32);
    a4 += __shfl_xor(a4, 32); a5 += __shfl_xor(a5, 32);
    a6 += __shfl_xor(a6, 32); a7 += __shfl_xor(a7, 32);
    if (lane < 16) {
      float* d = &smr[wave * 128 + lane * 8];
      d[0] = a0; d[1] = a1; d[2] = a2; d[3] = a3;
      d[4] = a4; d[5] = a5; d[6] = a6; d[7] = a7;
    }
    __syncthreads();
    if (tid < 128) {
      const float s =
          smr[tid] + smr[128 + tid] + smr[256 + tid] + smr[384 + tid];
      atomicAdd(&pooled[g * H + tid], s);
    }
    if (tid == 0) atomicAdd(&cnt[g], (float)(end - start));
    __syncthreads();
    start = end;
  }
}

// ---------------------------------------------------------------------------
// Head: pooled/cnt -> z = pooled@pw1+pb1 -> logits -> log_softmax
// ---------------------------------------------------------------------------
__global__ __launch_bounds__(128) void head_kernel(
    const float* __restrict__ pooled, const float* __restrict__ cnt,
    const float* __restrict__ pw1, const float* __restrict__ pb1,
    const float* __restrict__ pw2, const float* __restrict__ pb2,
    float* __restrict__ out_logp) {
  __shared__ float p[H];
  __shared__ float z[H];
  __shared__ float l[C];
  const int g = blockIdx.x;
  const int f = threadIdx.x;
  const float c = fmaxf(cnt[g], 1.f);
  p[f] = pooled[g * H + f] / c;
  __syncthreads();
  float a = pb1[f];
  for (int k = 0; k < H; ++k) a += p[k] * pw1[k * H + f];
  z[f] = a;
  __syncthreads();
  if (f < C) {
    float a2 = pb2[f];
    for (int k = 0; k < H; ++k) a2 += z[k] * pw2[k * C + f];
    l[f] = a2;
  }
  __syncthreads();
  if (f == 0) {
    float m = l[0];
    for (int i = 1; i < C; ++i) m = fmaxf(m, l[i]);
    float s = 0.f;
    for (int i = 0; i < C; ++i) s += expf(l[i] - m);
    const float lse = m + logf(s);
    for (int i = 0; i < C; ++i) out_logp[g * C + i] = l[i] - lse;
  }
}

extern "C" void kernel_launch(void* const* d_in, const int* in_sizes, int n_in,
                              void* d_out, int out_size, void* d_ws,
                              size_t ws_size, hipStream_t stream) {
  const float* x = (const float*)d_in[0];
  const int* ei = (const int*)d_in[1];
  const int* src = ei;
  const int* dst = ei + E;
  const int* batch = (const int*)d_in[2];
  const float* w1_0 = (const float*)d_in[3];
  const float* b1_0 = (const float*)d_in[4];
  const float* w2_0 = (const float*)d_in[5];
  const float* b2_0 = (const float*)d_in[6];
  const float* w1_1 = (const float*)d_in[7];
  const float* b1_1 = (const float*)d_in[8];
  const float* w2_1 = (const float*)d_in[9];
  const float* b2_1 = (const float*)d_in[10];
  const float* w1_2 = (const float*)d_in[11];
  const float* b1_2 = (const float*)d_in[12];
  const float* w2_2 = (const float*)d_in[13];
  const float* b2_2 = (const float*)d_in[14];
  const float* ln_g0 = (const float*)d_in[15];
  const float* ln_b0 = (const float*)d_in[16];
  const float* ln_g1 = (const float*)d_in[17];
  const float* ln_b1 = (const float*)d_in[18];
  const float* pw1 = (const float*)d_in[19];
  const float* pb1 = (const float*)d_in[20];
  const float* pw2 = (const float*)d_in[21];
  const float* pb2 = (const float*)d_in[22];

  unsigned short* xb = (unsigned short*)d_ws;          // N*H bf16
  unsigned short* hb = xb + (size_t)N * H;             // N*H bf16
  unsigned short* pre = hb + (size_t)N * H;            // N*H bf16
  float* pooled = (float*)(pre + (size_t)N * H);       // G*H
  float* cnt = pooled + (size_t)G * H;                 // G
  int* deg = (int*)(cnt + G);                          // N
  int* rowptr = deg + N;                               // N+1
  int* cursor = rowptr + N + 1;                        // N
  int* csr_src = cursor + N;                           // E
  int* partials = csr_src + E;                         // NBLK
  int* blockbase = partials + NBLK;                    // NBLK
  float* emb = (float*)d_out;                          // N*H fp32
  float* logp = emb + (size_t)N * H;                   // G*C

  // ---- x -> bf16 ----
  tobf_kernel<<<N * H / (256 * 8), 256, 0, stream>>>(x, (uint4*)xb);

  // ---- CSR build ----
  hipMemsetAsync(deg, 0, (size_t)N * sizeof(int), stream);
  hist_kernel<<<HCHUNK * HPART, 256, 0, stream>>>(dst, deg);
  partial_kernel<<<NBLK, 256, 0, stream>>>(deg, partials);
  scanp_kernel<<<1, 512, 0, stream>>>(partials, blockbase);
  expand_kernel<<<NBLK, 256, 0, stream>>>(deg, blockbase, rowptr, cursor);
  fill_kernel<<<FCHUNK * FPART, 256, 0, stream>>>(src, dst, cursor, csr_src);

  // ---- conv 0 ----
  gather_kernel<<<N / 16, 256, 0, stream>>>((const uint4*)xb, rowptr, csr_src,
                                            (uint4*)pre);
  mlp_kernel<0><<<640, 256, 0, stream>>>(pre, w1_0, b1_0, w2_0, b2_0, ln_g0,
                                         ln_b0, hb, nullptr);
  // ---- conv 1 ----
  gather_kernel<<<N / 16, 256, 0, stream>>>((const uint4*)hb, rowptr, csr_src,
                                            (uint4*)pre);
  mlp_kernel<0><<<640, 256, 0, stream>>>(pre, w1_1, b1_1, w2_1, b2_1, ln_g1,
                                         ln_b1, hb, nullptr);
  // ---- conv 2 ----
  gather_kernel<<<N / 16, 256, 0, stream>>>((const uint4*)hb, rowptr, csr_src,
                                            (uint4*)pre);
  mlp_kernel<1><<<640, 256, 0, stream>>>(pre, w1_2, b1_2, w2_2, b2_2, nullptr,
                                         nullptr, hb, emb);

  // ---- pool + head ----
  hipMemsetAsync(pooled, 0, (size_t)(G * H + G) * sizeof(float), stream);
  pool_kernel<<<NBLK, 256, 0, stream>>>((const uint4*)hb, batch, pooled, cnt);
  head_kernel<<<G, 128, 0, stream>>>(pooled, cnt, pw1, pb1, pw2, pb2, logp);
}

// Round 9
// 575.127 us; speedup vs baseline: 1.1637x; 1.0618x over previous
//
#include <hip/hip_runtime.h>

typedef __bf16 bf16_t;
typedef __bf16 bf16x8 __attribute__((ext_vector_type(8)));
typedef float floatx4 __attribute__((ext_vector_type(4)));

constexpr int N = 100000;   // nodes
constexpr int E = 1600000;  // edges
constexpr int H = 128;      // feature dim
constexpr int G = 64;       // graphs
constexpr int C = 10;       // classes
constexpr int NBLK = (N + 255) / 256;  // 391

// fill: 8 partitions (cursor+csr slice L2-resident), 256 edge chunks.
constexpr int FPART = 8;
constexpr int FPART_SZ = (N + FPART - 1) / FPART;  // 12500
constexpr int FCHUNK = 256;
constexpr int FCHUNK_E = E / FCHUNK;     // 6250

__device__ inline float bflo(unsigned u) {
  return __builtin_bit_cast(float, u << 16);
}
__device__ inline float bfhi(unsigned u) {
  return __builtin_bit_cast(float, u & 0xffff0000u);
}
__device__ inline unsigned short f2b(float f) {
  return __builtin_bit_cast(unsigned short, (bf16_t)f);
}
__device__ inline unsigned pack2(float a, float b) {
  return (unsigned)f2b(a) | ((unsigned)f2b(b) << 16);
}

// ---------------------------------------------------------------------------
// fp32 -> bf16 convert (x once per call).
// ---------------------------------------------------------------------------
__global__ __launch_bounds__(256) void tobf_kernel(const float* __restrict__ x,
                                                   uint4* __restrict__ xb) {
  const int g = blockIdx.x * 256 + threadIdx.x;
  const float4 a = *(const float4*)(x + (size_t)g * 8);
  const float4 b = *(const float4*)(x + (size_t)g * 8 + 4);
  uint4 o;
  o.x = pack2(a.x, a.y);
  o.y = pack2(a.z, a.w);
  o.z = pack2(b.x, b.y);
  o.w = pack2(b.z, b.w);
  xb[g] = o;
}

// ---------------------------------------------------------------------------
// Histogram: direct global atomics, one pass over dst. 1.6M atomics at
// ~76 G/s measured -> ~21 us; the LDS-privatized version (R7) was 102 us
// (16x dst re-read, latency-bound). Simple wins here.
// ---------------------------------------------------------------------------
__global__ __launch_bounds__(256) void hist_kernel(const int* __restrict__ dst,
                                                   int* __restrict__ deg) {
  const int e = blockIdx.x * 256 + threadIdx.x;
  if (e < E) atomicAdd(&deg[dst[e]], 1);
}

__global__ __launch_bounds__(256) void partial_kernel(
    const int* __restrict__ deg, int* __restrict__ partials) {
  __shared__ int sm[256];
  const int tid = threadIdx.x;
  const int i = blockIdx.x * 256 + tid;
  sm[tid] = (i < N) ? deg[i] : 0;
  __syncthreads();
  for (int off = 128; off > 0; off >>= 1) {
    if (tid < off) sm[tid] += sm[tid + off];
    __syncthreads();
  }
  if (tid == 0) partials[blockIdx.x] = sm[0];
}

__global__ __launch_bounds__(512) void scanp_kernel(
    const int* __restrict__ partials, int* __restrict__ blockbase) {
  __shared__ int p[512];
  const int t = threadIdx.x;
  p[t] = (t < NBLK) ? partials[t] : 0;
  __syncthreads();
  for (int off = 1; off < 512; off <<= 1) {
    int v = 0;
    if (t >= off) v = p[t - off];
    __syncthreads();
    p[t] += v;
    __syncthreads();
  }
  if (t < NBLK) blockbase[t] = (t == 0) ? 0 : p[t - 1];
}

__global__ __launch_bounds__(256) void expand_kernel(
    const int* __restrict__ deg, const int* __restrict__ blockbase,
    int* __restrict__ rowptr, int* __restrict__ cursor) {
  __shared__ int sm[256];
  const int tid = threadIdx.x;
  const int i = blockIdx.x * 256 + tid;
  const int d = (i < N) ? deg[i] : 0;
  sm[tid] = d;
  __syncthreads();
  for (int off = 1; off < 256; off <<= 1) {
    int v = 0;
    if (tid >= off) v = sm[tid - off];
    __syncthreads();
    sm[tid] += v;
    __syncthreads();
  }
  const int excl = sm[tid] - d + blockbase[blockIdx.x];
  if (i < N) {
    rowptr[i] = excl;
    cursor[i] = excl;
  }
  if (i == N - 1) rowptr[N] = excl + d;
}

// ---------------------------------------------------------------------------
// Partitioned fill: blockIdx&7 = dst range (XCD-pinned cursor/csr slice);
// nontemporal src/dst reads so the stream doesn't evict dirty csr lines.
// ---------------------------------------------------------------------------
__global__ __launch_bounds__(256) void fill_kernel(const int* __restrict__ src,
                                                   const int* __restrict__ dst,
                                                   int* __restrict__ cursor,
                                                   int* __restrict__ csr_src) {
  const int part = blockIdx.x & (FPART - 1);
  const int chunk = blockIdx.x >> 3;
  const int lo = part * FPART_SZ;
  const int hi = lo + FPART_SZ;
  const int c0 = chunk * FCHUNK_E;
  for (int e = c0 + threadIdx.x; e < c0 + FCHUNK_E; e += 256) {
    const int d = __builtin_nontemporal_load(dst + e);
    if (d >= lo && d < hi) {
      const int s = __builtin_nontemporal_load(src + e);
      const int slot = atomicAdd(&cursor[d], 1);
      csr_src[slot] = s;
    }
  }
}

// ---------------------------------------------------------------------------
// Gather aggregation (bf16): pre[i] = h[i] + sum_{j in nbrs(i)} h[j]
// 16 lanes/node, uint4 (8 bf16)/lane, unroll 4 (4 row-loads in flight).
// ---------------------------------------------------------------------------
__global__ __launch_bounds__(256) void gather_kernel(
    const uint4* __restrict__ h, const int* __restrict__ rowptr,
    const int* __restrict__ csr_src, uint4* __restrict__ pre) {
  const int node = blockIdx.x * 16 + (threadIdx.x >> 4);
  const int l = threadIdx.x & 15;
  const int r0 = rowptr[node];
  const int r1 = rowptr[node + 1];
  const uint4 v = h[(size_t)node * 16 + l];
  float a0 = bflo(v.x), a1 = bfhi(v.x), a2 = bflo(v.y), a3 = bfhi(v.y);
  float a4 = bflo(v.z), a5 = bfhi(v.z), a6 = bflo(v.w), a7 = bfhi(v.w);
  int s = r0;
  for (; s + 3 < r1; s += 4) {
    const int i0 = csr_src[s], i1 = csr_src[s + 1];
    const int i2 = csr_src[s + 2], i3 = csr_src[s + 3];
    const uint4 u0 = h[(size_t)i0 * 16 + l];
    const uint4 u1 = h[(size_t)i1 * 16 + l];
    const uint4 u2 = h[(size_t)i2 * 16 + l];
    const uint4 u3 = h[(size_t)i3 * 16 + l];
    a0 += bflo(u0.x); a1 += bfhi(u0.x); a2 += bflo(u0.y); a3 += bfhi(u0.y);
    a4 += bflo(u0.z); a5 += bfhi(u0.z); a6 += bflo(u0.w); a7 += bfhi(u0.w);
    a0 += bflo(u1.x); a1 += bfhi(u1.x); a2 += bflo(u1.y); a3 += bfhi(u1.y);
    a4 += bflo(u1.z); a5 += bfhi(u1.z); a6 += bflo(u1.w); a7 += bfhi(u1.w);
    a0 += bflo(u2.x); a1 += bfhi(u2.x); a2 += bflo(u2.y); a3 += bfhi(u2.y);
    a4 += bflo(u2.z); a5 += bfhi(u2.z); a6 += bflo(u2.w); a7 += bfhi(u2.w);
    a0 += bflo(u3.x); a1 += bfhi(u3.x); a2 += bflo(u3.y); a3 += bfhi(u3.y);
    a4 += bflo(u3.z); a5 += bfhi(u3.z); a6 += bflo(u3.w); a7 += bfhi(u3.w);
  }
  for (; s < r1; ++s) {
    const uint4 u = h[(size_t)csr_src[s] * 16 + l];
    a0 += bflo(u.x); a1 += bfhi(u.x); a2 += bflo(u.y); a3 += bfhi(u.y);
    a4 += bflo(u.z); a5 += bfhi(u.z); a6 += bflo(u.w); a7 += bfhi(u.w);
  }
  uint4 o;
  o.x = pack2(a0, a1);
  o.y = pack2(a2, a3);
  o.z = pack2(a4, a5);
  o.w = pack2(a6, a7);
  pre[(size_t)node * 16 + l] = o;
}

// ---------------------------------------------------------------------------
// MFMA bf16 GIN MLP. 32-node tiles; W1/W2 register fragments; preS/hidS rows
// padded to 136 shorts; outS rows padded to 132 floats.
// MODE 0: h_out = bf16(LN(relu(o))); MODE 1: emb = o (fp32), h_out = relu(o).
// ---------------------------------------------------------------------------
template <int MODE>
__global__ __launch_bounds__(256, 1) void mlp_kernel(
    const unsigned short* __restrict__ pre_g,  // bf16 N x 128
    const float* __restrict__ w1, const float* __restrict__ b1,
    const float* __restrict__ w2, const float* __restrict__ b2,
    const float* __restrict__ lng, const float* __restrict__ lnb,
    unsigned short* __restrict__ h_out,        // bf16 N x 128
    float* __restrict__ emb) {
  __shared__ unsigned short preS[32 * 136];
  __shared__ unsigned short hidS[32 * 136];
  __shared__ float outS[32 * 132];
  __shared__ float muS[32];
  __shared__ float rsS[32];

  const int tid = threadIdx.x;
  const int wave = tid >> 6;
  const int lane = tid & 63;
  const int quad = lane >> 4;
  const int l16 = lane & 15;

  union F8 { bf16x8 v; bf16_t e[8]; };

  bf16x8 w1f[4][2], w2f[4][2];
#pragma unroll
  for (int nn = 0; nn < 2; ++nn) {
    const int col = wave * 32 + nn * 16 + l16;
#pragma unroll
    for (int kt = 0; kt < 4; ++kt) {
      F8 t1, t2;
#pragma unroll
      for (int j = 0; j < 8; ++j) {
        const int k = kt * 32 + quad * 8 + j;
        t1.e[j] = (bf16_t)w1[k * H + col];
        t2.e[j] = (bf16_t)w2[k * H + col];
      }
      w1f[kt][nn] = t1.v;
      w2f[kt][nn] = t2.v;
    }
  }
  const float b1v[2] = {b1[wave * 32 + l16], b1[wave * 32 + 16 + l16]};
  const float b2v[2] = {b2[wave * 32 + l16], b2[wave * 32 + 16 + l16]};
  float lng0 = 0.f, lng1 = 0.f, lnb0 = 0.f, lnb1 = 0.f;
  const int c2 = (tid * 2) & 127;
  if (MODE == 0) {
    lng0 = lng[c2]; lng1 = lng[c2 + 1];
    lnb0 = lnb[c2]; lnb1 = lnb[c2 + 1];
  }

  for (int tile = blockIdx.x; tile < N / 32; tile += gridDim.x) {
    const size_t base = (size_t)tile * 32 * H;
    {
      const uint4* srcp = (const uint4*)(pre_g + base);
#pragma unroll
      for (int it = 0; it < 2; ++it) {
        const int chunk = it * 256 + tid;
        const int row = chunk >> 4;
        const int colc = (chunk & 15) * 8;
        *(uint4*)&preS[row * 136 + colc] = srcp[chunk];
      }
    }
    __syncthreads();

    // GEMM1: hid = relu(pre @ W1 + b1)
    {
      floatx4 acc[2][2];
#pragma unroll
      for (int i = 0; i < 2; ++i)
#pragma unroll
        for (int j = 0; j < 2; ++j) acc[i][j] = {0.f, 0.f, 0.f, 0.f};
#pragma unroll
      for (int kt = 0; kt < 4; ++kt) {
        const int kc = kt * 32 + quad * 8;
        const bf16x8 a0 =
            __builtin_bit_cast(bf16x8, *(const uint4*)&preS[l16 * 136 + kc]);
        const bf16x8 a1 = __builtin_bit_cast(
            bf16x8, *(const uint4*)&preS[(16 + l16) * 136 + kc]);
        acc[0][0] = __builtin_amdgcn_mfma_f32_16x16x32_bf16(a0, w1f[kt][0],
                                                            acc[0][0], 0, 0, 0);
        acc[0][1] = __builtin_amdgcn_mfma_f32_16x16x32_bf16(a0, w1f[kt][1],
                                                            acc[0][1], 0, 0, 0);
        acc[1][0] = __builtin_amdgcn_mfma_f32_16x16x32_bf16(a1, w1f[kt][0],
                                                            acc[1][0], 0, 0, 0);
        acc[1][1] = __builtin_amdgcn_mfma_f32_16x16x32_bf16(a1, w1f[kt][1],
                                                            acc[1][1], 0, 0, 0);
      }
#pragma unroll
      for (int mt = 0; mt < 2; ++mt)
#pragma unroll
        for (int nn = 0; nn < 2; ++nn) {
          const int col = wave * 32 + nn * 16 + l16;
#pragma unroll
          for (int r = 0; r < 4; ++r) {
            const int row = mt * 16 + quad * 4 + r;
            const float v = fmaxf(acc[mt][nn][r] + b1v[nn], 0.f);
            hidS[row * 136 + col] = f2b(v);
          }
        }
    }
    __syncthreads();

    // GEMM2: o = hid @ W2 + b2
    {
      floatx4 acc[2][2];
#pragma unroll
      for (int i = 0; i < 2; ++i)
#pragma unroll
        for (int j = 0; j < 2; ++j) acc[i][j] = {0.f, 0.f, 0.f, 0.f};
#pragma unroll
      for (int kt = 0; kt < 4; ++kt) {
        const int kc = kt * 32 + quad * 8;
        const bf16x8 a0 =
            __builtin_bit_cast(bf16x8, *(const uint4*)&hidS[l16 * 136 + kc]);
        const bf16x8 a1 = __builtin_bit_cast(
            bf16x8, *(const uint4*)&hidS[(16 + l16) * 136 + kc]);
        acc[0][0] = __builtin_amdgcn_mfma_f32_16x16x32_bf16(a0, w2f[kt][0],
                                                            acc[0][0], 0, 0, 0);
        acc[0][1] = __builtin_amdgcn_mfma_f32_16x16x32_bf16(a0, w2f[kt][1],
                                                            acc[0][1], 0, 0, 0);
        acc[1][0] = __builtin_amdgcn_mfma_f32_16x16x32_bf16(a1, w2f[kt][0],
                                                            acc[1][0], 0, 0, 0);
        acc[1][1] = __builtin_amdgcn_mfma_f32_16x16x32_bf16(a1, w2f[kt][1],
                                                            acc[1][1], 0, 0, 0);
      }
#pragma unroll
      for (int mt = 0; mt < 2; ++mt)
#pragma unroll
        for (int nn = 0; nn < 2; ++nn) {
          const int col = wave * 32 + nn * 16 + l16;
#pragma unroll
          for (int r = 0; r < 4; ++r) {
            const int row = mt * 16 + quad * 4 + r;
            float v = acc[mt][nn][r] + b2v[nn];
            if (MODE == 0) v = fmaxf(v, 0.f);
            outS[row * 132 + col] = v;
          }
        }
    }
    __syncthreads();

    if (MODE == 0) {
      const int n = tid >> 3;
      const int j = tid & 7;
      float s = 0.f, sq = 0.f;
#pragma unroll
      for (int t = 0; t < 16; ++t) {
        const float v = outS[n * 132 + j + 8 * t];
        s += v;
        sq += v * v;
      }
      s += __shfl_xor(s, 1); sq += __shfl_xor(sq, 1);
      s += __shfl_xor(s, 2); sq += __shfl_xor(sq, 2);
      s += __shfl_xor(s, 4); sq += __shfl_xor(sq, 4);
      if (j == 0) {
        const float mu = s * (1.f / H);
        const float var = sq * (1.f / H) - mu * mu;
        muS[n] = mu;
        rsS[n] = rsqrtf(var + 1e-5f);
      }
      __syncthreads();
      unsigned* ho = (unsigned*)(h_out + base);
#pragma unroll
      for (int it = 0; it < 8; ++it) {
        const int idx = it * 512 + tid * 2;
        const int row = idx >> 7;
        const int k = idx & 127;
        const float mu = muS[row], rs = rsS[row];
        const float v0 = (outS[row * 132 + k] - mu) * rs * lng0 + lnb0;
        const float v1 = (outS[row * 132 + k + 1] - mu) * rs * lng1 + lnb1;
        ho[idx >> 1] = pack2(v0, v1);
      }
    } else {
      unsigned* ho = (unsigned*)(h_out + base);
#pragma unroll
      for (int it = 0; it < 8; ++it) {
        const int idx = it * 512 + tid * 2;
        const int row = idx >> 7;
        const int k = idx & 127;
        const float v0 = outS[row * 132 + k];
        const float v1 = outS[row * 132 + k + 1];
        *(float2*)&emb[base + idx] = make_float2(v0, v1);
        ho[idx >> 1] = pack2(fmaxf(v0, 0.f), fmaxf(v1, 0.f));
      }
    }
    __syncthreads();
  }
}

// ---------------------------------------------------------------------------
// Mean pool: cooperative segmented reduction over sorted `batch`.
// ---------------------------------------------------------------------------
__global__ __launch_bounds__(256) void pool_kernel(
    const uint4* __restrict__ hv, const int* __restrict__ batch,
    float* __restrict__ pooled, float* __restrict__ cnt) {
  __shared__ int bs[256];
  __shared__ float smr[512];
  __shared__ int endS;
  const int tid = threadIdx.x;
  const int c0 = blockIdx.x * 256;
  const int len = min(256, N - c0);
  if (tid < len) bs[tid] = batch[c0 + tid];
  __syncthreads();

  const int nl = tid >> 4;
  const int fg = tid & 15;
  const int wave = tid >> 6;
  const int lane = tid & 63;

  int start = 0;
  while (start < len) {
    const int g = bs[start];
    if (tid == 0) endS = len;
    __syncthreads();
    for (int i = start + tid; i < len; i += 256)
      if (bs[i] != g) atomicMin(&endS, i);
    __syncthreads();
    const int end = endS;

    float a0 = 0.f, a1 = 0.f, a2 = 0.f, a3 = 0.f;
    float a4 = 0.f, a5 = 0.f, a6 = 0.f, a7 = 0.f;
    for (int i = start + nl; i < end; i += 16) {
      const uint4 u = hv[(size_t)(c0 + i) * 16 + fg];
      a0 += bflo(u.x); a1 += bfhi(u.x); a2 += bflo(u.y); a3 += bfhi(u.y);
      a4 += bflo(u.z); a5 += bfhi(u.z); a6 += bflo(u.w); a7 += bfhi(u.w);
    }
    a0 += __shfl_xor(a0, 16); a1 += __shfl_xor(a1, 16);
    a2 += __shfl_xor(a2, 16); a3 += __shfl_xor(a3, 16);
    a4 += __shfl_xor(a4, 16); a5 += __shfl_xor(a5, 16);
    a6 += __shfl_xor(a6, 16); a7 += __shfl_xor(a7, 16);
    a0 += __shfl_xor(a0, 32); a1 += __shfl_xor(a1, 32);
    a2 += __shfl_xor(a2, 32); a3 += __shfl_xor(a3, 32);
    a4 += __shfl_xor(a4, 32); a5 += __shfl_xor(a5, 32);
    a6 += __shfl_xor(a6, 32); a7 += __shfl_xor(a7, 32);
    if (lane < 16) {
      float* d = &smr[wave * 128 + lane * 8];
      d[0] = a0; d[1] = a1; d[2] = a2; d[3] = a3;
      d[4] = a4; d[5] = a5; d[6] = a6; d[7] = a7;
    }
    __syncthreads();
    if (tid < 128) {
      const float s =
          smr[tid] + smr[128 + tid] + smr[256 + tid] + smr[384 + tid];
      atomicAdd(&pooled[g * H + tid], s);
    }
    if (tid == 0) atomicAdd(&cnt[g], (float)(end - start));
    __syncthreads();
    start = end;
  }
}

// ---------------------------------------------------------------------------
// Head: pooled/cnt -> z = pooled@pw1+pb1 -> logits -> log_softmax
// ---------------------------------------------------------------------------
__global__ __launch_bounds__(128) void head_kernel(
    const float* __restrict__ pooled, const float* __restrict__ cnt,
    const float* __restrict__ pw1, const float* __restrict__ pb1,
    const float* __restrict__ pw2, const float* __restrict__ pb2,
    float* __restrict__ out_logp) {
  __shared__ float p[H];
  __shared__ float z[H];
  __shared__ float l[C];
  const int g = blockIdx.x;
  const int f = threadIdx.x;
  const float c = fmaxf(cnt[g], 1.f);
  p[f] = pooled[g * H + f] / c;
  __syncthreads();
  float a = pb1[f];
  for (int k = 0; k < H; ++k) a += p[k] * pw1[k * H + f];
  z[f] = a;
  __syncthreads();
  if (f < C) {
    float a2 = pb2[f];
    for (int k = 0; k < H; ++k) a2 += z[k] * pw2[k * C + f];
    l[f] = a2;
  }
  __syncthreads();
  if (f == 0) {
    float m = l[0];
    for (int i = 1; i < C; ++i) m = fmaxf(m, l[i]);
    float s = 0.f;
    for (int i = 0; i < C; ++i) s += expf(l[i] - m);
    const float lse = m + logf(s);
    for (int i = 0; i < C; ++i) out_logp[g * C + i] = l[i] - lse;
  }
}

extern "C" void kernel_launch(void* const* d_in, const int* in_sizes, int n_in,
                              void* d_out, int out_size, void* d_ws,
                              size_t ws_size, hipStream_t stream) {
  const float* x = (const float*)d_in[0];
  const int* ei = (const int*)d_in[1];
  const int* src = ei;
  const int* dst = ei + E;
  const int* batch = (const int*)d_in[2];
  const float* w1_0 = (const float*)d_in[3];
  const float* b1_0 = (const float*)d_in[4];
  const float* w2_0 = (const float*)d_in[5];
  const float* b2_0 = (const float*)d_in[6];
  const float* w1_1 = (const float*)d_in[7];
  const float* b1_1 = (const float*)d_in[8];
  const float* w2_1 = (const float*)d_in[9];
  const float* b2_1 = (const float*)d_in[10];
  const float* w1_2 = (const float*)d_in[11];
  const float* b1_2 = (const float*)d_in[12];
  const float* w2_2 = (const float*)d_in[13];
  const float* b2_2 = (const float*)d_in[14];
  const float* ln_g0 = (const float*)d_in[15];
  const float* ln_b0 = (const float*)d_in[16];
  const float* ln_g1 = (const float*)d_in[17];
  const float* ln_b1 = (const float*)d_in[18];
  const float* pw1 = (const float*)d_in[19];
  const float* pb1 = (const float*)d_in[20];
  const float* pw2 = (const float*)d_in[21];
  const float* pb2 = (const float*)d_in[22];

  unsigned short* xb = (unsigned short*)d_ws;          // N*H bf16
  unsigned short* hb = xb + (size_t)N * H;             // N*H bf16
  unsigned short* pre = hb + (size_t)N * H;            // N*H bf16
  float* pooled = (float*)(pre + (size_t)N * H);       // G*H
  float* cnt = pooled + (size_t)G * H;                 // G
  int* deg = (int*)(cnt + G);                          // N
  int* rowptr = deg + N;                               // N+1
  int* cursor = rowptr + N + 1;                        // N
  int* csr_src = cursor + N;                           // E
  int* partials = csr_src + E;                         // NBLK
  int* blockbase = partials + NBLK;                    // NBLK
  float* emb = (float*)d_out;                          // N*H fp32
  float* logp = emb + (size_t)N * H;                   // G*C

  // ---- x -> bf16 ----
  tobf_kernel<<<N * H / (256 * 8), 256, 0, stream>>>(x, (uint4*)xb);

  // ---- CSR build ----
  hipMemsetAsync(deg, 0, (size_t)N * sizeof(int), stream);
  hist_kernel<<<E / 256, 256, 0, stream>>>(dst, deg);
  partial_kernel<<<NBLK, 256, 0, stream>>>(deg, partials);
  scanp_kernel<<<1, 512, 0, stream>>>(partials, blockbase);
  expand_kernel<<<NBLK, 256, 0, stream>>>(deg, blockbase, rowptr, cursor);
  fill_kernel<<<FCHUNK * FPART, 256, 0, stream>>>(src, dst, cursor, csr_src);

  // ---- conv 0 ----
  gather_kernel<<<N / 16, 256, 0, stream>>>((const uint4*)xb, rowptr, csr_src,
                                            (uint4*)pre);
  mlp_kernel<0><<<640, 256, 0, stream>>>(pre, w1_0, b1_0, w2_0, b2_0, ln_g0,
                                         ln_b0, hb, nullptr);
  // ---- conv 1 ----
  gather_kernel<<<N / 16, 256, 0, stream>>>((const uint4*)hb, rowptr, csr_src,
                                            (uint4*)pre);
  mlp_kernel<0><<<640, 256, 0, stream>>>(pre, w1_1, b1_1, w2_1, b2_1, ln_g1,
                                         ln_b1, hb, nullptr);
  // ---- conv 2 ----
  gather_kernel<<<N / 16, 256, 0, stream>>>((const uint4*)hb, rowptr, csr_src,
                                            (uint4*)pre);
  mlp_kernel<1><<<640, 256, 0, stream>>>(pre, w1_2, b1_2, w2_2, b2_2, nullptr,
                                         nullptr, hb, emb);

  // ---- pool + head ----
  hipMemsetAsync(pooled, 0, (size_t)(G * H + G) * sizeof(float), stream);
  pool_kernel<<<NBLK, 256, 0, stream>>>((const uint4*)hb, batch, pooled, cnt);
  head_kernel<<<G, 128, 0, stream>>>(pooled, cnt, pw1, pb1, pw2, pb2, logp);
}

// Round 10
// 573.427 us; speedup vs baseline: 1.1671x; 1.0030x over previous
//
#include <hip/hip_runtime.h>

typedef __bf16 bf16_t;
typedef __bf16 bf16x8 __attribute__((ext_vector_type(8)));
typedef float floatx4 __attribute__((ext_vector_type(4)));

constexpr int N = 100000;   // nodes
constexpr int E = 1600000;  // edges
constexpr int H = 128;      // feature dim
constexpr int G = 64;       // graphs
constexpr int C = 10;       // classes
constexpr int NBLK = (N + 255) / 256;  // 391

// fill: 8 partitions (cursor+csr slice L2-resident), 256 edge chunks.
constexpr int FPART = 8;
constexpr int FPART_SZ = (N + FPART - 1) / FPART;  // 12500
constexpr int FCHUNK = 256;
constexpr int FCHUNK_E = E / FCHUNK;     // 6250

__device__ inline float bflo(unsigned u) {
  return __builtin_bit_cast(float, u << 16);
}
__device__ inline float bfhi(unsigned u) {
  return __builtin_bit_cast(float, u & 0xffff0000u);
}
__device__ inline unsigned short f2b(float f) {
  return __builtin_bit_cast(unsigned short, (bf16_t)f);
}
__device__ inline unsigned pack2(float a, float b) {
  return (unsigned)f2b(a) | ((unsigned)f2b(b) << 16);
}

// ---------------------------------------------------------------------------
// fp32 -> bf16 convert (x once per call).
// ---------------------------------------------------------------------------
__global__ __launch_bounds__(256) void tobf_kernel(const float* __restrict__ x,
                                                   uint4* __restrict__ xb) {
  const int g = blockIdx.x * 256 + threadIdx.x;
  const float4 a = *(const float4*)(x + (size_t)g * 8);
  const float4 b = *(const float4*)(x + (size_t)g * 8 + 4);
  uint4 o;
  o.x = pack2(a.x, a.y);
  o.y = pack2(a.z, a.w);
  o.z = pack2(b.x, b.y);
  o.w = pack2(b.z, b.w);
  xb[g] = o;
}

// ---------------------------------------------------------------------------
// Histogram: direct global atomics, one pass over dst.
// ---------------------------------------------------------------------------
__global__ __launch_bounds__(256) void hist_kernel(const int* __restrict__ dst,
                                                   int* __restrict__ deg) {
  const int e = blockIdx.x * 256 + threadIdx.x;
  if (e < E) atomicAdd(&deg[dst[e]], 1);
}

__global__ __launch_bounds__(256) void partial_kernel(
    const int* __restrict__ deg, int* __restrict__ partials) {
  __shared__ int sm[256];
  const int tid = threadIdx.x;
  const int i = blockIdx.x * 256 + tid;
  sm[tid] = (i < N) ? deg[i] : 0;
  __syncthreads();
  for (int off = 128; off > 0; off >>= 1) {
    if (tid < off) sm[tid] += sm[tid + off];
    __syncthreads();
  }
  if (tid == 0) partials[blockIdx.x] = sm[0];
}

__global__ __launch_bounds__(512) void scanp_kernel(
    const int* __restrict__ partials, int* __restrict__ blockbase) {
  __shared__ int p[512];
  const int t = threadIdx.x;
  p[t] = (t < NBLK) ? partials[t] : 0;
  __syncthreads();
  for (int off = 1; off < 512; off <<= 1) {
    int v = 0;
    if (t >= off) v = p[t - off];
    __syncthreads();
    p[t] += v;
    __syncthreads();
  }
  if (t < NBLK) blockbase[t] = (t == 0) ? 0 : p[t - 1];
}

__global__ __launch_bounds__(256) void expand_kernel(
    const int* __restrict__ deg, const int* __restrict__ blockbase,
    int* __restrict__ rowptr, int* __restrict__ cursor) {
  __shared__ int sm[256];
  const int tid = threadIdx.x;
  const int i = blockIdx.x * 256 + tid;
  const int d = (i < N) ? deg[i] : 0;
  sm[tid] = d;
  __syncthreads();
  for (int off = 1; off < 256; off <<= 1) {
    int v = 0;
    if (tid >= off) v = sm[tid - off];
    __syncthreads();
    sm[tid] += v;
    __syncthreads();
  }
  const int excl = sm[tid] - d + blockbase[blockIdx.x];
  if (i < N) {
    rowptr[i] = excl;
    cursor[i] = excl;
  }
  if (i == N - 1) rowptr[N] = excl + d;
}

// ---------------------------------------------------------------------------
// Partitioned fill: blockIdx&7 = dst range (XCD-pinned cursor/csr slice);
// nontemporal src/dst reads.
// ---------------------------------------------------------------------------
__global__ __launch_bounds__(256) void fill_kernel(const int* __restrict__ src,
                                                   const int* __restrict__ dst,
                                                   int* __restrict__ cursor,
                                                   int* __restrict__ csr_src) {
  const int part = blockIdx.x & (FPART - 1);
  const int chunk = blockIdx.x >> 3;
  const int lo = part * FPART_SZ;
  const int hi = lo + FPART_SZ;
  const int c0 = chunk * FCHUNK_E;
  for (int e = c0 + threadIdx.x; e < c0 + FCHUNK_E; e += 256) {
    const int d = __builtin_nontemporal_load(dst + e);
    if (d >= lo && d < hi) {
      const int s = __builtin_nontemporal_load(src + e);
      const int slot = atomicAdd(&cursor[d], 1);
      csr_src[slot] = s;
    }
  }
}

// ---------------------------------------------------------------------------
// Gather aggregation (bf16): pre[i] = h[i] + sum_{j in nbrs(i)} h[j]
// 16 lanes/node, uint4 (8 bf16)/lane, unroll 4.
// ---------------------------------------------------------------------------
__global__ __launch_bounds__(256) void gather_kernel(
    const uint4* __restrict__ h, const int* __restrict__ rowptr,
    const int* __restrict__ csr_src, uint4* __restrict__ pre) {
  const int node = blockIdx.x * 16 + (threadIdx.x >> 4);
  const int l = threadIdx.x & 15;
  const int r0 = rowptr[node];
  const int r1 = rowptr[node + 1];
  const uint4 v = h[(size_t)node * 16 + l];
  float a0 = bflo(v.x), a1 = bfhi(v.x), a2 = bflo(v.y), a3 = bfhi(v.y);
  float a4 = bflo(v.z), a5 = bfhi(v.z), a6 = bflo(v.w), a7 = bfhi(v.w);
  int s = r0;
  for (; s + 3 < r1; s += 4) {
    const int i0 = csr_src[s], i1 = csr_src[s + 1];
    const int i2 = csr_src[s + 2], i3 = csr_src[s + 3];
    const uint4 u0 = h[(size_t)i0 * 16 + l];
    const uint4 u1 = h[(size_t)i1 * 16 + l];
    const uint4 u2 = h[(size_t)i2 * 16 + l];
    const uint4 u3 = h[(size_t)i3 * 16 + l];
    a0 += bflo(u0.x); a1 += bfhi(u0.x); a2 += bflo(u0.y); a3 += bfhi(u0.y);
    a4 += bflo(u0.z); a5 += bfhi(u0.z); a6 += bflo(u0.w); a7 += bfhi(u0.w);
    a0 += bflo(u1.x); a1 += bfhi(u1.x); a2 += bflo(u1.y); a3 += bfhi(u1.y);
    a4 += bflo(u1.z); a5 += bfhi(u1.z); a6 += bflo(u1.w); a7 += bfhi(u1.w);
    a0 += bflo(u2.x); a1 += bfhi(u2.x); a2 += bflo(u2.y); a3 += bfhi(u2.y);
    a4 += bflo(u2.z); a5 += bfhi(u2.z); a6 += bflo(u2.w); a7 += bfhi(u2.w);
    a0 += bflo(u3.x); a1 += bfhi(u3.x); a2 += bflo(u3.y); a3 += bfhi(u3.y);
    a4 += bflo(u3.z); a5 += bfhi(u3.z); a6 += bflo(u3.w); a7 += bfhi(u3.w);
  }
  for (; s < r1; ++s) {
    const uint4 u = h[(size_t)csr_src[s] * 16 + l];
    a0 += bflo(u.x); a1 += bfhi(u.x); a2 += bflo(u.y); a3 += bfhi(u.y);
    a4 += bflo(u.z); a5 += bfhi(u.z); a6 += bflo(u.w); a7 += bfhi(u.w);
  }
  uint4 o;
  o.x = pack2(a0, a1);
  o.y = pack2(a2, a3);
  o.z = pack2(a4, a5);
  o.w = pack2(a6, a7);
  pre[(size_t)node * 16 + l] = o;
}

// ---------------------------------------------------------------------------
// MFMA bf16 GIN MLP, low-LDS version: only preS + hidS (bf16, 136-padded)
// + 64 floats of LN stats = 17.7 KB -> ~8 blocks/CU co-resident (was 65 KB,
// 2 blocks/CU). After GEMM2, o is written as bf16 back into preS (dead
// after GEMM1); LN stats computed from bf16 (adds ~0.008 abs err, slack ok).
// MODE 0: h_out = bf16(LN(relu(o))); MODE 1: emb = o, h_out = relu(o).
// ---------------------------------------------------------------------------
template <int MODE>
__global__ __launch_bounds__(256) void mlp_kernel(
    const unsigned short* __restrict__ pre_g,  // bf16 N x 128
    const float* __restrict__ w1, const float* __restrict__ b1,
    const float* __restrict__ w2, const float* __restrict__ b2,
    const float* __restrict__ lng, const float* __restrict__ lnb,
    unsigned short* __restrict__ h_out,        // bf16 N x 128
    float* __restrict__ emb) {
  __shared__ unsigned short preS[32 * 136];
  __shared__ unsigned short hidS[32 * 136];
  __shared__ float muS[32];
  __shared__ float rsS[32];

  const int tid = threadIdx.x;
  const int wave = tid >> 6;
  const int lane = tid & 63;
  const int quad = lane >> 4;
  const int l16 = lane & 15;

  union F8 { bf16x8 v; bf16_t e[8]; };

  bf16x8 w1f[4][2], w2f[4][2];
#pragma unroll
  for (int nn = 0; nn < 2; ++nn) {
    const int col = wave * 32 + nn * 16 + l16;
#pragma unroll
    for (int kt = 0; kt < 4; ++kt) {
      F8 t1, t2;
#pragma unroll
      for (int j = 0; j < 8; ++j) {
        const int k = kt * 32 + quad * 8 + j;
        t1.e[j] = (bf16_t)w1[k * H + col];
        t2.e[j] = (bf16_t)w2[k * H + col];
      }
      w1f[kt][nn] = t1.v;
      w2f[kt][nn] = t2.v;
    }
  }
  const float b1v[2] = {b1[wave * 32 + l16], b1[wave * 32 + 16 + l16]};
  const float b2v[2] = {b2[wave * 32 + l16], b2[wave * 32 + 16 + l16]};
  float lng0 = 0.f, lng1 = 0.f, lnb0 = 0.f, lnb1 = 0.f;
  const int c2 = (tid * 2) & 127;
  if (MODE == 0) {
    lng0 = lng[c2]; lng1 = lng[c2 + 1];
    lnb0 = lnb[c2]; lnb1 = lnb[c2 + 1];
  }

  for (int tile = blockIdx.x; tile < N / 32; tile += gridDim.x) {
    const size_t base = (size_t)tile * 32 * H;
    {
      const uint4* srcp = (const uint4*)(pre_g + base);
#pragma unroll
      for (int it = 0; it < 2; ++it) {
        const int chunk = it * 256 + tid;
        const int row = chunk >> 4;
        const int colc = (chunk & 15) * 8;
        *(uint4*)&preS[row * 136 + colc] = srcp[chunk];
      }
    }
    __syncthreads();

    // GEMM1: hid = relu(pre @ W1 + b1)
    {
      floatx4 acc[2][2];
#pragma unroll
      for (int i = 0; i < 2; ++i)
#pragma unroll
        for (int j = 0; j < 2; ++j) acc[i][j] = {0.f, 0.f, 0.f, 0.f};
#pragma unroll
      for (int kt = 0; kt < 4; ++kt) {
        const int kc = kt * 32 + quad * 8;
        const bf16x8 a0 =
            __builtin_bit_cast(bf16x8, *(const uint4*)&preS[l16 * 136 + kc]);
        const bf16x8 a1 = __builtin_bit_cast(
            bf16x8, *(const uint4*)&preS[(16 + l16) * 136 + kc]);
        acc[0][0] = __builtin_amdgcn_mfma_f32_16x16x32_bf16(a0, w1f[kt][0],
                                                            acc[0][0], 0, 0, 0);
        acc[0][1] = __builtin_amdgcn_mfma_f32_16x16x32_bf16(a0, w1f[kt][1],
                                                            acc[0][1], 0, 0, 0);
        acc[1][0] = __builtin_amdgcn_mfma_f32_16x16x32_bf16(a1, w1f[kt][0],
                                                            acc[1][0], 0, 0, 0);
        acc[1][1] = __builtin_amdgcn_mfma_f32_16x16x32_bf16(a1, w1f[kt][1],
                                                            acc[1][1], 0, 0, 0);
      }
#pragma unroll
      for (int mt = 0; mt < 2; ++mt)
#pragma unroll
        for (int nn = 0; nn < 2; ++nn) {
          const int col = wave * 32 + nn * 16 + l16;
#pragma unroll
          for (int r = 0; r < 4; ++r) {
            const int row = mt * 16 + quad * 4 + r;
            const float v = fmaxf(acc[mt][nn][r] + b1v[nn], 0.f);
            hidS[row * 136 + col] = f2b(v);
          }
        }
    }
    __syncthreads();  // hidS ready; also: all preS reads (GEMM1) done

    // GEMM2: o = hid @ W2 + b2 ; write o (bf16) back into preS
    {
      floatx4 acc[2][2];
#pragma unroll
      for (int i = 0; i < 2; ++i)
#pragma unroll
        for (int j = 0; j < 2; ++j) acc[i][j] = {0.f, 0.f, 0.f, 0.f};
#pragma unroll
      for (int kt = 0; kt < 4; ++kt) {
        const int kc = kt * 32 + quad * 8;
        const bf16x8 a0 =
            __builtin_bit_cast(bf16x8, *(const uint4*)&hidS[l16 * 136 + kc]);
        const bf16x8 a1 = __builtin_bit_cast(
            bf16x8, *(const uint4*)&hidS[(16 + l16) * 136 + kc]);
        acc[0][0] = __builtin_amdgcn_mfma_f32_16x16x32_bf16(a0, w2f[kt][0],
                                                            acc[0][0], 0, 0, 0);
        acc[0][1] = __builtin_amdgcn_mfma_f32_16x16x32_bf16(a0, w2f[kt][1],
                                                            acc[0][1], 0, 0, 0);
        acc[1][0] = __builtin_amdgcn_mfma_f32_16x16x32_bf16(a1, w2f[kt][0],
                                                            acc[1][0], 0, 0, 0);
        acc[1][1] = __builtin_amdgcn_mfma_f32_16x16x32_bf16(a1, w2f[kt][1],
                                                            acc[1][1], 0, 0, 0);
      }
#pragma unroll
      for (int mt = 0; mt < 2; ++mt)
#pragma unroll
        for (int nn = 0; nn < 2; ++nn) {
          const int col = wave * 32 + nn * 16 + l16;
#pragma unroll
          for (int r = 0; r < 4; ++r) {
            const int row = mt * 16 + quad * 4 + r;
            float v = acc[mt][nn][r] + b2v[nn];
            if (MODE == 0) v = fmaxf(v, 0.f);
            preS[row * 136 + col] = f2b(v);
          }
        }
    }
    __syncthreads();

    if (MODE == 0) {
      // LN stats from bf16 o in preS
      const int n = tid >> 3;
      const int j = tid & 7;
      float s = 0.f, sq = 0.f;
#pragma unroll
      for (int t = 0; t < 16; ++t) {
        const float v = bflo((unsigned)preS[n * 136 + j + 8 * t] << 16 >> 16 |
                             ((unsigned)preS[n * 136 + j + 8 * t] << 16));
        // (expression above folds to bf16->f32; keep simple instead:)
        (void)v;
      }
      s = 0.f; sq = 0.f;
#pragma unroll
      for (int t = 0; t < 16; ++t) {
        const float v =
            __builtin_bit_cast(float, (unsigned)preS[n * 136 + j + 8 * t] << 16);
        s += v;
        sq += v * v;
      }
      s += __shfl_xor(s, 1); sq += __shfl_xor(sq, 1);
      s += __shfl_xor(s, 2); sq += __shfl_xor(sq, 2);
      s += __shfl_xor(s, 4); sq += __shfl_xor(sq, 4);
      if (j == 0) {
        const float mu = s * (1.f / H);
        const float var = sq * (1.f / H) - mu * mu;
        muS[n] = mu;
        rsS[n] = rsqrtf(var + 1e-5f);
      }
      __syncthreads();
      unsigned* ho = (unsigned*)(h_out + base);
#pragma unroll
      for (int it = 0; it < 8; ++it) {
        const int idx = it * 512 + tid * 2;
        const int row = idx >> 7;
        const int k = idx & 127;
        const unsigned pr = *(const unsigned*)&preS[row * 136 + k];
        const float mu = muS[row], rs = rsS[row];
        const float v0 = (bflo(pr) - mu) * rs * lng0 + lnb0;
        const float v1 = (bfhi(pr) - mu) * rs * lng1 + lnb1;
        ho[idx >> 1] = pack2(v0, v1);
      }
    } else {
      unsigned* ho = (unsigned*)(h_out + base);
#pragma unroll
      for (int it = 0; it < 8; ++it) {
        const int idx = it * 512 + tid * 2;
        const int row = idx >> 7;
        const int k = idx & 127;
        const unsigned pr = *(const unsigned*)&preS[row * 136 + k];
        const float v0 = bflo(pr);
        const float v1 = bfhi(pr);
        *(float2*)&emb[base + idx] = make_float2(v0, v1);
        ho[idx >> 1] = pack2(fmaxf(v0, 0.f), fmaxf(v1, 0.f));
      }
    }
    __syncthreads();
  }
}

// ---------------------------------------------------------------------------
// Mean pool: cooperative segmented reduction over sorted `batch`.
// ---------------------------------------------------------------------------
__global__ __launch_bounds__(256) void pool_kernel(
    const uint4* __restrict__ hv, const int* __restrict__ batch,
    float* __restrict__ pooled, float* __restrict__ cnt) {
  __shared__ int bs[256];
  __shared__ float smr[512];
  __shared__ int endS;
  const int tid = threadIdx.x;
  const int c0 = blockIdx.x * 256;
  const int len = min(256, N - c0);
  if (tid < len) bs[tid] = batch[c0 + tid];
  __syncthreads();

  const int nl = tid >> 4;
  const int fg = tid & 15;
  const int wave = tid >> 6;
  const int lane = tid & 63;

  int start = 0;
  while (start < len) {
    const int g = bs[start];
    if (tid == 0) endS = len;
    __syncthreads();
    for (int i = start + tid; i < len; i += 256)
      if (bs[i] != g) atomicMin(&endS, i);
    __syncthreads();
    const int end = endS;

    float a0 = 0.f, a1 = 0.f, a2 = 0.f, a3 = 0.f;
    float a4 = 0.f, a5 = 0.f, a6 = 0.f, a7 = 0.f;
    for (int i = start + nl; i < end; i += 16) {
      const uint4 u = hv[(size_t)(c0 + i) * 16 + fg];
      a0 += bflo(u.x); a1 += bfhi(u.x); a2 += bflo(u.y); a3 += bfhi(u.y);
      a4 += bflo(u.z); a5 += bfhi(u.z); a6 += bflo(u.w); a7 += bfhi(u.w);
    }
    a0 += __shfl_xor(a0, 16); a1 += __shfl_xor(a1, 16);
    a2 += __shfl_xor(a2, 16); a3 += __shfl_xor(a3, 16);
    a4 += __shfl_xor(a4, 16); a5 += __shfl_xor(a5, 16);
    a6 += __shfl_xor(a6, 16); a7 += __shfl_xor(a7, 16);
    a0 += __shfl_xor(a0, 32); a1 += __shfl_xor(a1, 32);
    a2 += __shfl_xor(a2, 32); a3 += __shfl_xor(a3, 32);
    a4 += __shfl_xor(a4, 32); a5 += __shfl_xor(a5, 32);
    a6 += __shfl_xor(a6, 32); a7 += __shfl_xor(a7, 32);
    if (lane < 16) {
      float* d = &smr[wave * 128 + lane * 8];
      d[0] = a0; d[1] = a1; d[2] = a2; d[3] = a3;
      d[4] = a4; d[5] = a5; d[6] = a6; d[7] = a7;
    }
    __syncthreads();
    if (tid < 128) {
      const float s =
          smr[tid] + smr[128 + tid] + smr[256 + tid] + smr[384 + tid];
      atomicAdd(&pooled[g * H + tid], s);
    }
    if (tid == 0) atomicAdd(&cnt[g], (float)(end - start));
    __syncthreads();
    start = end;
  }
}

// ---------------------------------------------------------------------------
// Head: pooled/cnt -> z = pooled@pw1+pb1 -> logits -> log_softmax
// ---------------------------------------------------------------------------
__global__ __launch_bounds__(128) void head_kernel(
    const float* __restrict__ pooled, const float* __restrict__ cnt,
    const float* __restrict__ pw1, const float* __restrict__ pb1,
    const float* __restrict__ pw2, const float* __restrict__ pb2,
    float* __restrict__ out_logp) {
  __shared__ float p[H];
  __shared__ float z[H];
  __shared__ float l[C];
  const int g = blockIdx.x;
  const int f = threadIdx.x;
  const float c = fmaxf(cnt[g], 1.f);
  p[f] = pooled[g * H + f] / c;
  __syncthreads();
  float a = pb1[f];
  for (int k = 0; k < H; ++k) a += p[k] * pw1[k * H + f];
  z[f] = a;
  __syncthreads();
  if (f < C) {
    float a2 = pb2[f];
    for (int k = 0; k < H; ++k) a2 += z[k] * pw2[k * C + f];
    l[f] = a2;
  }
  __syncthreads();
  if (f == 0) {
    float m = l[0];
    for (int i = 1; i < C; ++i) m = fmaxf(m, l[i]);
    float s = 0.f;
    for (int i = 0; i < C; ++i) s += expf(l[i] - m);
    const float lse = m + logf(s);
    for (int i = 0; i < C; ++i) out_logp[g * C + i] = l[i] - lse;
  }
}

extern "C" void kernel_launch(void* const* d_in, const int* in_sizes, int n_in,
                              void* d_out, int out_size, void* d_ws,
                              size_t ws_size, hipStream_t stream) {
  const float* x = (const float*)d_in[0];
  const int* ei = (const int*)d_in[1];
  const int* src = ei;
  const int* dst = ei + E;
  const int* batch = (const int*)d_in[2];
  const float* w1_0 = (const float*)d_in[3];
  const float* b1_0 = (const float*)d_in[4];
  const float* w2_0 = (const float*)d_in[5];
  const float* b2_0 = (const float*)d_in[6];
  const float* w1_1 = (const float*)d_in[7];
  const float* b1_1 = (const float*)d_in[8];
  const float* w2_1 = (const float*)d_in[9];
  const float* b2_1 = (const float*)d_in[10];
  const float* w1_2 = (const float*)d_in[11];
  const float* b1_2 = (const float*)d_in[12];
  const float* w2_2 = (const float*)d_in[13];
  const float* b2_2 = (const float*)d_in[14];
  const float* ln_g0 = (const float*)d_in[15];
  const float* ln_b0 = (const float*)d_in[16];
  const float* ln_g1 = (const float*)d_in[17];
  const float* ln_b1 = (const float*)d_in[18];
  const float* pw1 = (const float*)d_in[19];
  const float* pb1 = (const float*)d_in[20];
  const float* pw2 = (const float*)d_in[21];
  const float* pb2 = (const float*)d_in[22];

  unsigned short* xb = (unsigned short*)d_ws;          // N*H bf16
  unsigned short* hb = xb + (size_t)N * H;             // N*H bf16
  unsigned short* pre = hb + (size_t)N * H;            // N*H bf16
  float* pooled = (float*)(pre + (size_t)N * H);       // G*H
  float* cnt = pooled + (size_t)G * H;                 // G
  int* deg = (int*)(cnt + G);                          // N
  int* rowptr = deg + N;                               // N+1
  int* cursor = rowptr + N + 1;                        // N
  int* csr_src = cursor + N;                           // E
  int* partials = csr_src + E;                         // NBLK
  int* blockbase = partials + NBLK;                    // NBLK
  float* emb = (float*)d_out;                          // N*H fp32
  float* logp = emb + (size_t)N * H;                   // G*C

  // ---- x -> bf16 ----
  tobf_kernel<<<N * H / (256 * 8), 256, 0, stream>>>(x, (uint4*)xb);

  // ---- CSR build ----
  hipMemsetAsync(deg, 0, (size_t)N * sizeof(int), stream);
  hist_kernel<<<E / 256, 256, 0, stream>>>(dst, deg);
  partial_kernel<<<NBLK, 256, 0, stream>>>(deg, partials);
  scanp_kernel<<<1, 512, 0, stream>>>(partials, blockbase);
  expand_kernel<<<NBLK, 256, 0, stream>>>(deg, blockbase, rowptr, cursor);
  fill_kernel<<<FCHUNK * FPART, 256, 0, stream>>>(src, dst, cursor, csr_src);

  // ---- conv 0 ----
  gather_kernel<<<N / 16, 256, 0, stream>>>((const uint4*)xb, rowptr, csr_src,
                                            (uint4*)pre);
  mlp_kernel<0><<<2048, 256, 0, stream>>>(pre, w1_0, b1_0, w2_0, b2_0, ln_g0,
                                          ln_b0, hb, nullptr);
  // ---- conv 1 ----
  gather_kernel<<<N / 16, 256, 0, stream>>>((const uint4*)hb, rowptr, csr_src,
                                            (uint4*)pre);
  mlp_kernel<0><<<2048, 256, 0, stream>>>(pre, w1_1, b1_1, w2_1, b2_1, ln_g1,
                                          ln_b1, hb, nullptr);
  // ---- conv 2 ----
  gather_kernel<<<N / 16, 256, 0, stream>>>((const uint4*)hb, rowptr, csr_src,
                                            (uint4*)pre);
  mlp_kernel<1><<<2048, 256, 0, stream>>>(pre, w1_2, b1_2, w2_2, b2_2, nullptr,
                                          nullptr, hb, emb);

  // ---- pool + head ----
  hipMemsetAsync(pooled, 0, (size_t)(G * H + G) * sizeof(float), stream);
  pool_kernel<<<NBLK, 256, 0, stream>>>((const uint4*)hb, batch, pooled, cnt);
  head_kernel<<<G, 128, 0, stream>>>(pooled, cnt, pw1, pb1, pw2, pb2, logp);
}